// Round 1
// baseline (1420.731 us; speedup 1.0000x reference)
//
#include <hip/hip_runtime.h>
#include <math.h>

#define S8   8
#define C256 256
#define HW   23
#define NF   529      // 23*23
#define K9   2304     // 256*9
#define NP   544      // NF padded to multiple of 16 (and 16B-aligned rows)
#define DMAP 45       // 2*H-1

// ---------------- label / spatial map builder (45x45) ----------------
__global__ void build_maps(const float* __restrict__ wl, const float* __restrict__ wsp,
                           float* __restrict__ labelF, float* __restrict__ spatialF) {
  int idx = blockIdx.x * blockDim.x + threadIdx.x;
  if (idx >= DMAP * DMAP) return;
  int h = idx / DMAP, w = idx % DMAP;
  float dy = (float)(h - 22), dx = (float)(w - 22);
  float dist = sqrtf(dy * dy + dx * dx);
  float lab = 0.f, sp = 0.f;
#pragma unroll
  for (int b = 0; b < 9; ++b) {
    float bd = dist * 2.f - (float)b;          // BIN_DISP = 0.5
    float wt = fmaxf(0.f, 1.f - fabsf(bd));
    lab += wl[b] * wt;
    sp  += wsp[b] * wt;
  }
  float bd = dist * 2.f - 9.f;
  float wt = fminf(fmaxf(1.f + bd, 0.f), 1.f);
  lab += wl[9] * wt;
  sp  += wsp[9] * wt;
  labelF[idx] = lab;
  spatialF[idx] = sp;
}

// ---------------- im2col: X[s][k=c*9+j][yx] (row stride NP, pads zeroed) ----------------
__global__ void im2col(const float* __restrict__ feat, float* __restrict__ X) {
  int g = blockIdx.x * 256 + threadIdx.x;          // exactly S8*K9*NP threads
  int s  = g / (K9 * NP);
  int r  = g % (K9 * NP);
  int k  = r / NP;
  int yx = r % NP;
  float v = 0.f;
  if (yx < NF) {
    int c = k / 9, j = k % 9;
    int y = yx / HW + j / 3 - 1;
    int x = yx % HW + j % 3 - 1;
    if (y >= 0 && y < HW && x >= 0 && x < HW)
      v = feat[(((size_t)s * C256 + c) * HW + y) * HW + x];
  }
  X[g] = v;
}

// ---------------- float4 copy (filter -> d_out) ----------------
__global__ void copy_f4(const float4* __restrict__ src, float4* __restrict__ dst, int n4) {
  int g = blockIdx.x * 256 + threadIdx.x;
  if (g < n4) dst[g] = src[g];
}

// ---------------- GEMM type A: C[m=nf][n=yx] = A[m][k] * X[k][n]  (NN) ----------------
// EPI=1: scores -> R = mask*sw^2*(scores_act - label); also writes mask
// EPI=3: scores_grad -> Z = sw * mask * sg
template <int EPI>
__launch_bounds__(256)
__global__ void gemm_score(const float* __restrict__ A,    // [S][NF][K9]
                           const float* __restrict__ X,    // [S][K9][NP]
                           float* __restrict__ out,        // [S][NF][NP]  (R or Z)
                           float* __restrict__ maskbuf,    // [S][NF][NP]
                           const float* __restrict__ labelF,
                           const float* __restrict__ spatialF) {
  const int s  = blockIdx.z;
  const int m0 = blockIdx.x * 64;
  const int n0 = blockIdx.y * 64;
  const float* Ab = A + (size_t)s * NF * K9;
  const float* Bb = X + (size_t)s * K9 * NP;

  __shared__ float As[16][68];
  __shared__ float Bs[16][68];

  const int tid   = threadIdx.x;
  const int arow  = tid >> 2;          // 0..63 (m within tile)
  const int akoff = (tid & 3) * 4;     // 0,4,8,12
  const int brow  = tid >> 4;          // 0..15 (k within BK)
  const int bnoff = (tid & 15) * 4;    // 0..60
  const int tx = tid & 15, ty = tid >> 4;

  const int am = m0 + arow;
  const bool aval = (am < NF);
  const bool bval = (n0 + bnoff) < NP;
  const float* aptr = Ab + (size_t)am * K9 + akoff;
  const float* bptr = Bb + n0 + bnoff;

  float acc[4][4];
#pragma unroll
  for (int i = 0; i < 4; ++i)
#pragma unroll
    for (int j = 0; j < 4; ++j) acc[i][j] = 0.f;

  for (int k0 = 0; k0 < K9; k0 += 16) {
    float4 av = aval ? *(const float4*)(aptr + k0) : float4{0.f, 0.f, 0.f, 0.f};
    float4 bv = bval ? *(const float4*)(bptr + (size_t)(k0 + brow) * NP) : float4{0.f, 0.f, 0.f, 0.f};
    __syncthreads();
    As[akoff + 0][arow] = av.x; As[akoff + 1][arow] = av.y;
    As[akoff + 2][arow] = av.z; As[akoff + 3][arow] = av.w;
    *(float4*)&Bs[brow][bnoff] = bv;
    __syncthreads();
#pragma unroll
    for (int k = 0; k < 16; ++k) {
      float4 a4 = *(const float4*)&As[k][ty * 4];
      float4 b4 = *(const float4*)&Bs[k][tx * 4];
      float aa[4] = {a4.x, a4.y, a4.z, a4.w};
      float bb[4] = {b4.x, b4.y, b4.z, b4.w};
#pragma unroll
      for (int i = 0; i < 4; ++i)
#pragma unroll
        for (int j = 0; j < 4; ++j) acc[i][j] = fmaf(aa[i], bb[j], acc[i][j]);
    }
  }

#pragma unroll
  for (int i = 0; i < 4; ++i) {
    int nf = m0 + ty * 4 + i;
    if (nf >= NF) break;
    int a = nf / HW, b = nf - a * HW;
    size_t rowo = ((size_t)s * NF + nf) * NP;
#pragma unroll
    for (int j = 0; j < 4; ++j) {
      int yx = n0 + tx * 4 + j;
      if (yx >= NP) continue;
      if (yx >= NF) {                 // zero the K-pad columns
        out[rowo + yx] = 0.f;
        if (EPI == 1) maskbuf[rowo + yx] = 0.f;
        continue;
      }
      int y = yx / HW, x = yx - y * HW;
      int idx = (22 + y - a) * DMAP + (22 + x - b);
      float sw = spatialF[idx];
      if (EPI == 1) {
        float lm = labelF[idx];
        float sv = acc[i][j];
        float sa, m;
        if (nf == yx) { sa = sv; m = 1.f; }
        else {
          sa = 0.5f * fabsf(sv) + 0.5f * sv;
          m  = (sv > 0.f) ? 1.f : ((sv < 0.f) ? 0.f : 0.5f);
        }
        out[rowo + yx] = m * sw * sw * (sa - lm);
        maskbuf[rowo + yx] = m;
      } else {
        out[rowo + yx] = sw * maskbuf[rowo + yx] * acc[i][j];
      }
    }
  }
}

// ---------------- GEMM type B: FG[m=nf][n=k] = R[m][yx] * X[n][yx]  (NT) + reg*F ----------------
__launch_bounds__(256)
__global__ void gemm_fg(const float* __restrict__ R,   // [S][NF][NP]
                        const float* __restrict__ X,   // [S][K9][NP]
                        const float* __restrict__ F,   // [S][NF][K9]
                        const float* __restrict__ fregp,
                        float* __restrict__ FG) {      // [S][NF][K9]
  const int s  = blockIdx.z;
  const int m0 = blockIdx.x * 64;
  const int n0 = blockIdx.y * 64;
  const float* Ab = R + (size_t)s * NF * NP;
  const float* Bb = X + (size_t)s * K9 * NP;

  __shared__ float As[16][68];
  __shared__ float Bs[16][68];

  const int tid   = threadIdx.x;
  const int arow  = tid >> 2;
  const int akoff = (tid & 3) * 4;
  const int tx = tid & 15, ty = tid >> 4;

  const int am = m0 + arow;
  const bool aval = (am < NF);
  const float* aptr = Ab + (size_t)am * NP + akoff;
  const float* bptr = Bb + (size_t)(n0 + arow) * NP + akoff;  // n0+arow < 2304 always

  float acc[4][4];
#pragma unroll
  for (int i = 0; i < 4; ++i)
#pragma unroll
    for (int j = 0; j < 4; ++j) acc[i][j] = 0.f;

  for (int k0 = 0; k0 < NP; k0 += 16) {   // K = 544 (pads are zero)
    float4 av = aval ? *(const float4*)(aptr + k0) : float4{0.f, 0.f, 0.f, 0.f};
    float4 bv = *(const float4*)(bptr + k0);
    __syncthreads();
    As[akoff + 0][arow] = av.x; As[akoff + 1][arow] = av.y;
    As[akoff + 2][arow] = av.z; As[akoff + 3][arow] = av.w;
    Bs[akoff + 0][arow] = bv.x; Bs[akoff + 1][arow] = bv.y;
    Bs[akoff + 2][arow] = bv.z; Bs[akoff + 3][arow] = bv.w;
    __syncthreads();
#pragma unroll
    for (int k = 0; k < 16; ++k) {
      float4 a4 = *(const float4*)&As[k][ty * 4];
      float4 b4 = *(const float4*)&Bs[k][tx * 4];
      float aa[4] = {a4.x, a4.y, a4.z, a4.w};
      float bb[4] = {b4.x, b4.y, b4.z, b4.w};
#pragma unroll
      for (int i = 0; i < 4; ++i)
#pragma unroll
        for (int j = 0; j < 4; ++j) acc[i][j] = fmaf(aa[i], bb[j], acc[i][j]);
    }
  }

  float reg = fmaxf(fregp[0] * fregp[0], 1e-10f);
#pragma unroll
  for (int i = 0; i < 4; ++i) {
    int m = m0 + ty * 4 + i;
    if (m >= NF) break;
#pragma unroll
    for (int j = 0; j < 4; ++j) {
      int n = n0 + tx * 4 + j;   // always < 2304
      size_t o = ((size_t)s * NF + m) * K9 + n;
      FG[o] = acc[i][j] + reg * F[o];
    }
  }
}

// ---------------- row reductions ----------------
__global__ void reduce_num(const float* __restrict__ FG, float* __restrict__ num) {
  int row = blockIdx.x;                       // 0..S8*NF-1
  const float* p = FG + (size_t)row * K9;
  float sum = 0.f;
  for (int i = threadIdx.x; i < K9; i += 256) { float v = p[i]; sum += v * v; }
  __shared__ float red[256];
  red[threadIdx.x] = sum; __syncthreads();
  for (int st = 128; st > 0; st >>= 1) {
    if (threadIdx.x < st) red[threadIdx.x] += red[threadIdx.x + st];
    __syncthreads();
  }
  if (threadIdx.x == 0) num[row] = red[0];
}

__global__ void reduce_den(const float* __restrict__ Z, float* __restrict__ den) {
  int row = blockIdx.x;
  const float* p = Z + (size_t)row * NP;      // pads are zero
  float sum = 0.f;
  for (int i = threadIdx.x; i < NP; i += 256) { float v = p[i]; sum += v * v; }
  __shared__ float red[256];
  red[threadIdx.x] = sum; __syncthreads();
  for (int st = 128; st > 0; st >>= 1) {
    if (threadIdx.x < st) red[threadIdx.x] += red[threadIdx.x + st];
    __syncthreads();
  }
  if (threadIdx.x == 0) den[row] = red[0];
}

// ---------------- filter update ----------------
__global__ void update_f(float* __restrict__ F, const float* __restrict__ FG,
                         const float* __restrict__ num, const float* __restrict__ den,
                         const float* __restrict__ lsp, const float* __restrict__ fregp) {
  int g = blockIdx.x * 256 + threadIdx.x;   // float4 index, exactly S8*NF*K9/4
  int row = g / (K9 / 4);
  float reg = fmaxf(fregp[0] * fregp[0], 1e-10f);
  float nm = num[row], dn = den[row];
  float alpha = nm / fmaxf(dn + reg * nm, 1e-8f);
  float sa = expf(lsp[0]) * alpha;
  float4 f  = ((const float4*)F)[g];
  float4 gv = ((const float4*)FG)[g];
  f.x -= sa * gv.x; f.y -= sa * gv.y; f.z -= sa * gv.z; f.w -= sa * gv.w;
  ((float4*)F)[g] = f;
}

// ---------------- driver ----------------
extern "C" void kernel_launch(void* const* d_in, const int* in_sizes, int n_in,
                              void* d_out, int out_size, void* d_ws, size_t ws_size,
                              hipStream_t stream) {
  const float* filt = (const float*)d_in[0];
  const float* feat = (const float*)d_in[1];
  const float* wl   = (const float*)d_in[2];
  const float* wsp  = (const float*)d_in[3];
  const float* lsp  = (const float*)d_in[4];
  const float* frp  = (const float*)d_in[5];
  float* F  = (float*)d_out;
  float* ws = (float*)d_ws;

  float* labelF   = ws;                                   // 2048
  float* spatialF = ws + 2048;                            // 2048
  float* X        = ws + 4096;                            // S8*K9*NP = 10,027,008
  float* R        = X + (size_t)S8 * K9 * NP;             // S8*NF*NP = 2,302,208
  float* Mask     = R + (size_t)S8 * NF * NP;             // 2,302,208
  float* FG       = Mask + (size_t)S8 * NF * NP;          // S8*NF*K9 = 9,750,528
  float* num      = FG + (size_t)S8 * NF * K9;            // 4240
  float* den      = num + 4240;                           // 4240
  // total ~ 94 MB of ws

  build_maps<<<(DMAP * DMAP + 255) / 256, 256, 0, stream>>>(wl, wsp, labelF, spatialF);
  im2col<<<(S8 * K9 * NP) / 256, 256, 0, stream>>>(feat, X);
  copy_f4<<<(S8 * NF * K9 / 4) / 256, 256, 0, stream>>>((const float4*)filt, (float4*)F,
                                                        S8 * NF * K9 / 4);

  for (int it = 0; it < 2; ++it) {
    // scores + fused residual/mask epilogue
    gemm_score<1><<<dim3(9, 9, S8), 256, 0, stream>>>(F, X, R, Mask, labelF, spatialF);
    // filter_grad = R * X^T + reg*F
    gemm_fg<<<dim3(9, 36, S8), 256, 0, stream>>>(R, X, F, frp, FG);
    reduce_num<<<S8 * NF, 256, 0, stream>>>(FG, num);
    // scores_grad, masked -> Z (reuses R buffer)
    gemm_score<3><<<dim3(9, 9, S8), 256, 0, stream>>>(FG, X, R, Mask, labelF, spatialF);
    reduce_den<<<S8 * NF, 256, 0, stream>>>(R, den);
    update_f<<<(S8 * NF * K9 / 4) / 256, 256, 0, stream>>>(F, FG, num, den, lsp, frp);
  }
}

// Round 4
// 820.384 us; speedup vs baseline: 1.7318x; 1.7318x over previous
//
#include <hip/hip_runtime.h>
#include <math.h>

#define NF   529
#define K9   2304
#define NP   544
#define DMAP 45

typedef unsigned short ush;
typedef unsigned int u32;
typedef __bf16 bf8_t __attribute__((ext_vector_type(8)));
typedef float f4_t __attribute__((ext_vector_type(4)));

__device__ __forceinline__ ush f2bf(float f) {
  union { float f; u32 u; } v; v.f = f;
  u32 r = v.u + 0x7fffu + ((v.u >> 16) & 1u);
  return (ush)(r >> 16);
}
__device__ __forceinline__ float bf2f(ush h) {
  union { u32 u; float f; } v; v.u = ((u32)h) << 16;
  return v.f;
}
__device__ __forceinline__ void async16(const void* g, void* l) {
  __builtin_amdgcn_global_load_lds((const __attribute__((address_space(1))) u32*)g,
                                   (__attribute__((address_space(3))) u32*)l, 16, 0, 0);
}

// ---------------- label / spatial map builder (45x45) ----------------
__global__ void build_maps(const float* __restrict__ wl, const float* __restrict__ wsp,
                           float* __restrict__ labelF, float* __restrict__ spatialF) {
  int idx = blockIdx.x * blockDim.x + threadIdx.x;
  if (idx >= DMAP * DMAP) return;
  int h = idx / DMAP, w = idx % DMAP;
  float dy = (float)(h - 22), dx = (float)(w - 22);
  float dist = sqrtf(dy * dy + dx * dx);
  float lab = 0.f, sp = 0.f;
#pragma unroll
  for (int b = 0; b < 9; ++b) {
    float bd = dist * 2.f - (float)b;
    float wt = fmaxf(0.f, 1.f - fabsf(bd));
    lab += wl[b] * wt;
    sp  += wsp[b] * wt;
  }
  float bd = dist * 2.f - 9.f;
  float wt = fminf(fmaxf(1.f + bd, 0.f), 1.f);
  lab += wl[9] * wt;
  sp  += wsp[9] * wt;
  labelF[idx] = lab;
  spatialF[idx] = sp;
}

// ---- convert filter -> fp32 copy (d_out) + bf16 hi/lo planes [s][576][2304] ----
__global__ void convert_f(const float* __restrict__ filt, float* __restrict__ F,
                          ush* __restrict__ Fh, ush* __restrict__ Fl) {
  int g = blockIdx.x * 256 + threadIdx.x;   // exactly 8*529*2304 threads
  float v = filt[g];
  F[g] = v;
  int row = g / K9;
  int k = g - row * K9;
  int s = row / NF, m = row - s * NF;
  ush h = f2bf(v);
  size_t o = ((size_t)s * 576 + m) * K9 + k;
  Fh[o] = h;
  Fl[o] = f2bf(v - bf2f(h));
}

// ---- im2col + pack: Xbh/Xbl[s][2304][544], XTh/XTl[s][640][2304] (hi/lo) ----
__global__ void im2col_pack(const float* __restrict__ feat,
                            ush* __restrict__ Xbh, ush* __restrict__ Xbl,
                            ush* __restrict__ XTh, ush* __restrict__ XTl) {
  __shared__ float T[64][65];
  int s = blockIdx.z, k0 = blockIdx.y * 64, yx0 = blockIdx.x * 64;
  int t = threadIdx.x;
  int r = t >> 2, c4 = (t & 3) * 16;
  // phase 1: rows = k (channel*9+j), cols = yx
  int k = k0 + r;
  int ck = k / 9, j = k - ck * 9;
  int dy = j / 3 - 1, dx = j - (j / 3) * 3 - 1;
  const float* fb = feat + ((size_t)s * 256 + ck) * (23 * 23);
#pragma unroll
  for (int i = 0; i < 16; ++i) {
    int yx = yx0 + c4 + i;
    float v = 0.f;
    if (yx < NF) {
      int yy = yx / 23;
      int y = yy + dy, x = yx - yy * 23 + dx;
      if (y >= 0 && y < 23 && x >= 0 && x < 23) v = fb[y * 23 + x];
    }
    T[r][c4 + i] = v;
    if (yx < NP) {
      size_t o = ((size_t)s * K9 + k) * NP + yx;
      ush h = f2bf(v);
      Xbh[o] = h;
      Xbl[o] = f2bf(v - bf2f(h));
    }
  }
  __syncthreads();
  // phase 2: rows = yx (0..639, zeros beyond 528), cols = k
#pragma unroll
  for (int i = 0; i < 16; ++i) {
    float v = T[c4 + i][r];
    ush h = f2bf(v);
    size_t o = ((size_t)s * 640 + yx0 + r) * K9 + k0 + c4 + i;
    XTh[o] = h;
    XTl[o] = f2bf(v - bf2f(h));
  }
}

// ---------------- generic MFMA GEMM, 256 thr, BN=128, BK=32 ----------------
// EPI=1: scores -> Rbh/Rbl (split residuals) + Mb (mask)
// EPI=2: filter_grad (+reg*F) -> FGh/FGl (split) + num (atomic row sumsq)
// EPI=3: scores_grad -> den (atomic row sum of (sw*mask*v)^2)
template <int BM, int AROWS, int BROWS, int KTOT, int ASPL, int BSPL, int FULL, int EPI>
__launch_bounds__(256, 2)
__global__ void gemm_mfma(const ush* __restrict__ Ah, const ush* __restrict__ Al,
                          const ush* __restrict__ Bh, const ush* __restrict__ Bl,
                          const float* __restrict__ labelF, const float* __restrict__ spatialF,
                          ush* __restrict__ Rbh, ush* __restrict__ Rbl, ush* __restrict__ Mb,
                          const float* __restrict__ F, const float* __restrict__ frp,
                          ush* __restrict__ FGh, ush* __restrict__ FGl,
                          float* __restrict__ numb, float* __restrict__ denb) {
  constexpr int MT = BM / 32;   // 16-row m tiles per wave
  constexpr int AI = BM / 64;   // 64-row staging groups for A
  constexpr int NCH = KTOT / 32;

  __shared__ ush As[ASPL][BM * 32];
  __shared__ ush Bs[BSPL][128 * 32];

  const int tid = threadIdx.x;
  const int w = tid >> 6, l = tid & 63;
  const int wm = w & 1, wn = w >> 1;
  const int q = l >> 4, c = l & 15;
  const int s = blockIdx.z;
  const int m0 = blockIdx.x * BM, n0 = blockIdx.y * 128;

  const ush* A0 = Ah + (size_t)s * AROWS * KTOT;
  const ush* A1 = (ASPL == 2) ? (Al + (size_t)s * AROWS * KTOT) : nullptr;
  const ush* B0 = Bh + (size_t)s * BROWS * KTOT;
  const ush* B1 = (BSPL == 2) ? (Bl + (size_t)s * BROWS * KTOT) : nullptr;

  const int srow = w * 16 + (l >> 2);     // row within 64-row staging group
  const int scol = (l & 3) * 8;           // 16B column segment

  f4_t acc[MT][4];
#pragma unroll
  for (int i = 0; i < MT; ++i)
#pragma unroll
    for (int jj = 0; jj < 4; ++jj) acc[i][jj] = (f4_t){0.f, 0.f, 0.f, 0.f};

  for (int ch = 0; ch < NCH; ++ch) {
    const int k0 = ch * 32;
    __syncthreads();
#pragma unroll
    for (int i = 0; i < AI; ++i) {
      size_t go = (size_t)(m0 + i * 64 + srow) * KTOT + k0 + scol;
      async16(A0 + go, &As[0][i * 2048 + w * 512]);
      if (ASPL == 2) async16(A1 + go, &As[1][i * 2048 + w * 512]);
    }
#pragma unroll
    for (int i = 0; i < 2; ++i) {
      size_t go = (size_t)(n0 + i * 64 + srow) * KTOT + k0 + scol;
      async16(B0 + go, &Bs[0][i * 2048 + w * 512]);
      if (BSPL == 2) async16(B1 + go, &Bs[1][i * 2048 + w * 512]);
    }
    __syncthreads();

    bf8_t av[ASPL][MT], bv[BSPL][4];
#pragma unroll
    for (int p = 0; p < ASPL; ++p)
#pragma unroll
      for (int ti = 0; ti < MT; ++ti)
        av[p][ti] = *(const bf8_t*)&As[p][(wm * (MT * 16) + ti * 16 + c) * 32 + q * 8];
#pragma unroll
    for (int p = 0; p < BSPL; ++p)
#pragma unroll
      for (int tj = 0; tj < 4; ++tj)
        bv[p][tj] = *(const bf8_t*)&Bs[p][(wn * 64 + tj * 16 + c) * 32 + q * 8];

#pragma unroll
    for (int ti = 0; ti < MT; ++ti)
#pragma unroll
      for (int tj = 0; tj < 4; ++tj) {
        acc[ti][tj] = __builtin_amdgcn_mfma_f32_16x16x32_bf16(av[0][ti], bv[0][tj], acc[ti][tj], 0, 0, 0);
        if (ASPL == 2)
          acc[ti][tj] = __builtin_amdgcn_mfma_f32_16x16x32_bf16(av[1][ti], bv[0][tj], acc[ti][tj], 0, 0, 0);
        if (BSPL == 2)
          acc[ti][tj] = __builtin_amdgcn_mfma_f32_16x16x32_bf16(av[0][ti], bv[1][tj], acc[ti][tj], 0, 0, 0);
        if (FULL)
          acc[ti][tj] = __builtin_amdgcn_mfma_f32_16x16x32_bf16(av[1][ti], bv[1][tj], acc[ti][tj], 0, 0, 0);
      }
  }

  if (EPI == 1) {
#pragma unroll
    for (int ti = 0; ti < MT; ++ti)
#pragma unroll
      for (int tj = 0; tj < 4; ++tj)
#pragma unroll
        for (int r = 0; r < 4; ++r) {
          int m = m0 + wm * (MT * 16) + ti * 16 + q * 4 + r;
          int n = n0 + wn * 64 + tj * 16 + c;
          if (m < NF && n < NF) {
            float v = acc[ti][tj][r];
            int a = m / 23, b = m - a * 23;
            int y = n / 23, x = n - y * 23;
            int idx = (22 + y - a) * DMAP + (22 + x - b);
            float sw = spatialF[idx], lm = labelF[idx];
            float sa, msk;
            if (m == n) { sa = v; msk = 1.f; }
            else {
              sa = 0.5f * fabsf(v) + 0.5f * v;
              msk = (v > 0.f) ? 1.f : ((v < 0.f) ? 0.f : 0.5f);
            }
            float rv = msk * sw * sw * (sa - lm);
            size_t o = ((size_t)s * 640 + m) * NP + n;
            ush h = f2bf(rv);
            Rbh[o] = h;
            Rbl[o] = f2bf(rv - bf2f(h));
            Mb[((size_t)s * NF + m) * NP + n] = f2bf(msk);
          }
        }
  } else if (EPI == 2) {
    float reg = fmaxf(frp[0] * frp[0], 1e-10f);
#pragma unroll
    for (int ti = 0; ti < MT; ++ti) {
      float ps[4] = {0.f, 0.f, 0.f, 0.f};
      int mb = m0 + wm * (MT * 16) + ti * 16 + q * 4;
#pragma unroll
      for (int tj = 0; tj < 4; ++tj) {
        int n = n0 + wn * 64 + tj * 16 + c;
#pragma unroll
        for (int r = 0; r < 4; ++r) {
          int m = mb + r;
          if (m < NF) {
            float v = acc[ti][tj][r] + reg * F[((size_t)s * NF + m) * K9 + n];
            size_t o = ((size_t)s * 576 + m) * K9 + n;
            ush h = f2bf(v);
            FGh[o] = h;
            FGl[o] = f2bf(v - bf2f(h));
            ps[r] += v * v;
          }
        }
      }
#pragma unroll
      for (int r = 0; r < 4; ++r) {
        float p = ps[r];
        p += __shfl_xor(p, 1); p += __shfl_xor(p, 2);
        p += __shfl_xor(p, 4); p += __shfl_xor(p, 8);
        if (c == 0 && (mb + r) < NF) atomicAdd(&numb[s * NF + mb + r], p);
      }
    }
  } else {
#pragma unroll
    for (int ti = 0; ti < MT; ++ti) {
      float ps[4] = {0.f, 0.f, 0.f, 0.f};
      int mb = m0 + wm * (MT * 16) + ti * 16 + q * 4;
#pragma unroll
      for (int tj = 0; tj < 4; ++tj) {
        int n = n0 + wn * 64 + tj * 16 + c;
#pragma unroll
        for (int r = 0; r < 4; ++r) {
          int m = mb + r;
          if (m < NF && n < NF) {
            int a = m / 23, b = m - a * 23;
            int y = n / 23, x = n - y * 23;
            int idx = (22 + y - a) * DMAP + (22 + x - b);
            float sw = spatialF[idx];
            float msk = bf2f(Mb[((size_t)s * NF + m) * NP + n]);
            float z = sw * msk * acc[ti][tj][r];
            ps[r] += z * z;
          }
        }
      }
#pragma unroll
      for (int r = 0; r < 4; ++r) {
        float p = ps[r];
        p += __shfl_xor(p, 1); p += __shfl_xor(p, 2);
        p += __shfl_xor(p, 4); p += __shfl_xor(p, 8);
        if (c == 0 && (mb + r) < NF) atomicAdd(&denb[s * NF + mb + r], p);
      }
    }
  }
}

// ---------------- filter update (+ refresh hi/lo planes) ----------------
__global__ void update_f(float* __restrict__ F, const ush* __restrict__ FGh,
                         const ush* __restrict__ FGl,
                         const float* __restrict__ numb, const float* __restrict__ denb,
                         const float* __restrict__ lsp, const float* __restrict__ frp,
                         ush* __restrict__ Fh, ush* __restrict__ Fl) {
  int g = blockIdx.x * 256 + threadIdx.x;  // 8*529*2304 threads
  int row = g / K9;
  int k = g - row * K9;
  int s = row / NF, m = row - s * NF;
  float reg = fmaxf(frp[0] * frp[0], 1e-10f);
  float nm = numb[row], dn = denb[row];
  float alpha = nm / fmaxf(dn + reg * nm, 1e-8f);
  float sa = expf(lsp[0]) * alpha;
  size_t o = ((size_t)s * 576 + m) * K9 + k;
  float gv = bf2f(FGh[o]) + bf2f(FGl[o]);
  float f = F[g] - sa * gv;
  F[g] = f;
  ush h = f2bf(f);
  Fh[o] = h;
  Fl[o] = f2bf(f - bf2f(h));
}

// ---------------- driver ----------------
extern "C" void kernel_launch(void* const* d_in, const int* in_sizes, int n_in,
                              void* d_out, int out_size, void* d_ws, size_t ws_size,
                              hipStream_t stream) {
  const float* filt = (const float*)d_in[0];
  const float* feat = (const float*)d_in[1];
  const float* wl   = (const float*)d_in[2];
  const float* wsp  = (const float*)d_in[3];
  const float* lsp  = (const float*)d_in[4];
  const float* frp  = (const float*)d_in[5];
  float* F = (float*)d_out;

  float* fb       = (float*)d_ws;
  float* labelF   = fb;
  float* spatialF = fb + 2048;
  float* numden   = fb + 4096;             // [2 iters][num|den][4240]
  ush* cur = (ush*)(fb + 4096 + 4 * 4240);

  const size_t szF  = (size_t)8 * 576 * K9;    // 10,616,832
  const size_t szXT = (size_t)8 * 640 * K9;    // 11,796,480
  const size_t szXb = (size_t)8 * K9 * NP;     // 10,027,008
  const size_t szRb = (size_t)8 * 640 * NP;    //  2,785,280
  const size_t szMb = (size_t)8 * NF * NP;     //  2,302,208

  ush* Fh  = cur;            cur += szF;
  ush* Fl  = cur;            cur += szF;
  ush* XTh = cur;            cur += szXT;
  ush* XTl = cur;            cur += szXT;
  ush* Xbh = cur;            cur += szXb;
  ush* Xbl = cur;            cur += szXb;
  ush* Rbh = cur;            cur += szRb;
  ush* Rbl = cur;            cur += szRb;
  ush* Mb  = cur;            cur += szMb;
  ush* FGh = cur;            cur += szF;
  ush* FGl = cur;            cur += szF;
  // total ~188 MB

  build_maps<<<8, 256, 0, stream>>>(wl, wsp, labelF, spatialF);
  hipMemsetAsync(numden, 0, 4 * 4240 * sizeof(float), stream);
  convert_f<<<(8 * NF * K9) / 256, 256, 0, stream>>>(filt, F, Fh, Fl);
  im2col_pack<<<dim3(10, 36, 8), 256, 0, stream>>>(feat, Xbh, Xbl, XTh, XTl);

  for (int it = 0; it < 2; ++it) {
    float* numb = numden + it * 2 * 4240;
    float* denb = numb + 4240;
    // scores (4-product split bf16, sign-exact) -> Rbh/Rbl, Mb
    gemm_mfma<64, 576, 640, K9, 2, 2, 1, 1><<<dim3(9, 5, 8), 256, 0, stream>>>(
        Fh, Fl, XTh, XTl, labelF, spatialF, Rbh, Rbl, Mb,
        nullptr, nullptr, nullptr, nullptr, nullptr, nullptr);
    // filter_grad = R*X^T + reg*F (3-product split) -> FGh/FGl + num
    gemm_mfma<128, 640, K9, NP, 2, 2, 0, 2><<<dim3(5, 18, 8), 256, 0, stream>>>(
        Rbh, Rbl, Xbh, Xbl, nullptr, nullptr, nullptr, nullptr, nullptr,
        F, frp, FGh, FGl, numb, nullptr);
    // scores_grad (2-product: A split, B hi) -> den
    gemm_mfma<64, 576, 640, K9, 2, 1, 0, 3><<<dim3(9, 5, 8), 256, 0, stream>>>(
        FGh, FGl, XTh, nullptr, nullptr, spatialF, nullptr, nullptr, Mb,
        nullptr, nullptr, nullptr, nullptr, nullptr, denb);
    update_f<<<(8 * NF * K9) / 256, 256, 0, stream>>>(F, FGh, FGl, numb, denb, lsp, frp, Fh, Fl);
  }
}

// Round 5
// 785.336 us; speedup vs baseline: 1.8091x; 1.0446x over previous
//
#include <hip/hip_runtime.h>
#include <math.h>

#define NF   529
#define K9   2304
#define NP   544
#define DMAP 45

typedef unsigned short ush;
typedef unsigned int u32;
typedef __bf16 bf8_t __attribute__((ext_vector_type(8)));
typedef float f4_t __attribute__((ext_vector_type(4)));
typedef ush ush8 __attribute__((ext_vector_type(8)));

__device__ __forceinline__ ush f2bf(float f) {
  union { float f; u32 u; } v; v.f = f;
  u32 r = v.u + 0x7fffu + ((v.u >> 16) & 1u);
  return (ush)(r >> 16);
}
__device__ __forceinline__ float bf2f(ush h) {
  union { u32 u; float f; } v; v.u = ((u32)h) << 16;
  return v.f;
}
__device__ __forceinline__ void async16(const void* g, void* l) {
  __builtin_amdgcn_global_load_lds((const __attribute__((address_space(1))) u32*)g,
                                   (__attribute__((address_space(3))) u32*)l, 16, 0, 0);
}

// ---------------- label / spatial map builder (45x45) ----------------
__global__ void build_maps(const float* __restrict__ wl, const float* __restrict__ wsp,
                           float* __restrict__ labelF, float* __restrict__ spatialF) {
  int idx = blockIdx.x * blockDim.x + threadIdx.x;
  if (idx >= DMAP * DMAP) return;
  int h = idx / DMAP, w = idx % DMAP;
  float dy = (float)(h - 22), dx = (float)(w - 22);
  float dist = sqrtf(dy * dy + dx * dx);
  float lab = 0.f, sp = 0.f;
#pragma unroll
  for (int b = 0; b < 9; ++b) {
    float bd = dist * 2.f - (float)b;
    float wt = fmaxf(0.f, 1.f - fabsf(bd));
    lab += wl[b] * wt;
    sp  += wsp[b] * wt;
  }
  float bd = dist * 2.f - 9.f;
  float wt = fminf(fmaxf(1.f + bd, 0.f), 1.f);
  lab += wl[9] * wt;
  sp  += wsp[9] * wt;
  labelF[idx] = lab;
  spatialF[idx] = sp;
}

// ---- convert filter -> fp32 copy (d_out) + bf16 hi/lo planes [s][576][2304] ----
// 8 elems / thread, 16B stores. grid: 8*529*2304/8/256 = 4761 blocks.
__global__ void convert_f(const float* __restrict__ filt, float* __restrict__ F,
                          ush* __restrict__ Fh, ush* __restrict__ Fl) {
  int g = blockIdx.x * 256 + threadIdx.x;
  int row = g / 288;                 // 2304/8 segments per row
  int kk = (g - row * 288) * 8;
  int s = row / NF, m = row - s * NF;
  const float4* fp = (const float4*)(filt + (size_t)row * K9 + kk);
  float4 a = fp[0], b = fp[1];
  float4* Fp = (float4*)(F + (size_t)row * K9 + kk);
  Fp[0] = a; Fp[1] = b;
  float vv[8] = {a.x, a.y, a.z, a.w, b.x, b.y, b.z, b.w};
  ush8 h, lo;
#pragma unroll
  for (int i = 0; i < 8; ++i) {
    ush hh = f2bf(vv[i]);
    h[i] = hh;
    lo[i] = f2bf(vv[i] - bf2f(hh));
  }
  size_t o = ((size_t)s * 576 + m) * K9 + kk;
  *(ush8*)(Fh + o) = h;
  *(ush8*)(Fl + o) = lo;
}

// ---- im2col + pack: Xbh/Xbl[s][2304][544], XTh/XTl[s][640][2304] (hi/lo) ----
// all global stores are 16B vectors
__global__ void im2col_pack(const float* __restrict__ feat,
                            ush* __restrict__ Xbh, ush* __restrict__ Xbl,
                            ush* __restrict__ XTh, ush* __restrict__ XTl) {
  __shared__ float T[64][65];
  int s = blockIdx.z, k0 = blockIdx.y * 64, yx0 = blockIdx.x * 64;
  int t = threadIdx.x;
  int r = t >> 2, c4 = (t & 3) * 16;
  int k = k0 + r;
  int ck = k / 9, j = k - ck * 9;
  int dy = j / 3 - 1, dx = j - (j / 3) * 3 - 1;
  const float* fb = feat + ((size_t)s * 256 + ck) * 529;
  float v[16];
#pragma unroll
  for (int i = 0; i < 16; ++i) {
    int yx = yx0 + c4 + i;
    float vv = 0.f;
    if (yx < NF) {
      int yy = yx / 23;
      int y = yy + dy, x = yx - yy * 23 + dx;
      if (y >= 0 && y < 23 && x >= 0 && x < 23) vv = fb[y * 23 + x];
    }
    v[i] = vv;
    T[r][c4 + i] = vv;
  }
  if (yx0 + c4 < NP) {
    size_t o = ((size_t)s * K9 + k) * NP + yx0 + c4;
    ush8 h[2], lo[2];
#pragma unroll
    for (int gg = 0; gg < 2; ++gg)
#pragma unroll
      for (int i = 0; i < 8; ++i) {
        float vv = v[gg * 8 + i];
        ush hh = f2bf(vv);
        h[gg][i] = hh;
        lo[gg][i] = f2bf(vv - bf2f(hh));
      }
    *(ush8*)(Xbh + o) = h[0];
    *(ush8*)(Xbh + o + 8) = h[1];
    *(ush8*)(Xbl + o) = lo[0];
    *(ush8*)(Xbl + o + 8) = lo[1];
  }
  __syncthreads();
  // phase 2: XT row = yx0 + r, cols k0+c4..+15
  size_t o2 = ((size_t)s * 640 + yx0 + r) * K9 + k0 + c4;
  ush8 h2[2], l2[2];
#pragma unroll
  for (int gg = 0; gg < 2; ++gg)
#pragma unroll
    for (int i = 0; i < 8; ++i) {
      float vv = T[c4 + gg * 8 + i][r];
      ush hh = f2bf(vv);
      h2[gg][i] = hh;
      l2[gg][i] = f2bf(vv - bf2f(hh));
    }
  *(ush8*)(XTh + o2) = h2[0];
  *(ush8*)(XTh + o2 + 8) = h2[1];
  *(ush8*)(XTl + o2) = l2[0];
  *(ush8*)(XTl + o2 + 8) = l2[1];
}

// ---------------- MFMA GEMM, 256 thr, BN=128, BK=32, double-buffered LDS ----------------
// EPI=1: scores -> Rbh/Rbl (split residuals) + Mb (mask)
// EPI=2: filter_grad (+reg*F) -> FGh/FGl (split) + num (atomic row sumsq)
// EPI=3: scores_grad -> den (atomic row sum of (sw*mask*v)^2)
template <int BM, int AROWS, int BROWS, int KTOT, int ASPL, int BSPL, int FULL, int EPI>
__launch_bounds__(256, 2)
__global__ void gemm_mfma(const ush* __restrict__ Ah, const ush* __restrict__ Al,
                          const ush* __restrict__ Bh, const ush* __restrict__ Bl,
                          const float* __restrict__ labelF, const float* __restrict__ spatialF,
                          ush* __restrict__ Rbh, ush* __restrict__ Rbl, ush* __restrict__ Mb,
                          const float* __restrict__ F, const float* __restrict__ frp,
                          ush* __restrict__ FGh, ush* __restrict__ FGl,
                          float* __restrict__ numb, float* __restrict__ denb) {
  constexpr int MT = BM / 32;   // 16-row m tiles per wave
  constexpr int AI = BM / 64;   // 64-row staging groups for A
  constexpr int NCH = KTOT / 32;

  __shared__ ush As[2][ASPL][BM * 32];
  __shared__ ush Bs[2][BSPL][128 * 32];

  const int tid = threadIdx.x;
  const int w = tid >> 6, l = tid & 63;
  const int wm = w & 1, wn = w >> 1;
  const int q = l >> 4, c = l & 15;
  const int s = blockIdx.z;
  const int m0 = blockIdx.x * BM, n0 = blockIdx.y * 128;

  const ush* A0 = Ah + (size_t)s * AROWS * KTOT;
  const ush* A1 = (ASPL == 2) ? (Al + (size_t)s * AROWS * KTOT) : nullptr;
  const ush* B0 = Bh + (size_t)s * BROWS * KTOT;
  const ush* B1 = (BSPL == 2) ? (Bl + (size_t)s * BROWS * KTOT) : nullptr;

  const int srow = w * 16 + (l >> 2);     // row within 64-row staging group
  const int scol = (l & 3) * 8;           // 16B column segment

  auto stage = [&](int ch, int buf) {
    const int k0 = ch * 32;
#pragma unroll
    for (int i = 0; i < AI; ++i) {
      size_t go = (size_t)(m0 + i * 64 + srow) * KTOT + k0 + scol;
      async16(A0 + go, &As[buf][0][i * 2048 + w * 512]);
      if (ASPL == 2) async16(A1 + go, &As[buf][1][i * 2048 + w * 512]);
    }
#pragma unroll
    for (int i = 0; i < 2; ++i) {
      size_t go = (size_t)(n0 + i * 64 + srow) * KTOT + k0 + scol;
      async16(B0 + go, &Bs[buf][0][i * 2048 + w * 512]);
      if (BSPL == 2) async16(B1 + go, &Bs[buf][1][i * 2048 + w * 512]);
    }
  };

  f4_t acc[MT][4];
#pragma unroll
  for (int i = 0; i < MT; ++i)
#pragma unroll
    for (int jj = 0; jj < 4; ++jj) acc[i][jj] = (f4_t){0.f, 0.f, 0.f, 0.f};

  stage(0, 0);
  __syncthreads();

  for (int ch = 0; ch < NCH; ++ch) {
    const int p = ch & 1;
    if (ch + 1 < NCH) stage(ch + 1, 1 - p);   // async prefetch into other buffer

    bf8_t av[ASPL][MT], bv[BSPL][4];
#pragma unroll
    for (int pp = 0; pp < ASPL; ++pp)
#pragma unroll
      for (int ti = 0; ti < MT; ++ti)
        av[pp][ti] = *(const bf8_t*)&As[p][pp][(wm * (MT * 16) + ti * 16 + c) * 32 + q * 8];
#pragma unroll
    for (int pp = 0; pp < BSPL; ++pp)
#pragma unroll
      for (int tj = 0; tj < 4; ++tj)
        bv[pp][tj] = *(const bf8_t*)&Bs[p][pp][(wn * 64 + tj * 16 + c) * 32 + q * 8];

#pragma unroll
    for (int ti = 0; ti < MT; ++ti)
#pragma unroll
      for (int tj = 0; tj < 4; ++tj) {
        acc[ti][tj] = __builtin_amdgcn_mfma_f32_16x16x32_bf16(av[0][ti], bv[0][tj], acc[ti][tj], 0, 0, 0);
        if (ASPL == 2)
          acc[ti][tj] = __builtin_amdgcn_mfma_f32_16x16x32_bf16(av[1][ti], bv[0][tj], acc[ti][tj], 0, 0, 0);
        if (BSPL == 2)
          acc[ti][tj] = __builtin_amdgcn_mfma_f32_16x16x32_bf16(av[0][ti], bv[1][tj], acc[ti][tj], 0, 0, 0);
        if (FULL)
          acc[ti][tj] = __builtin_amdgcn_mfma_f32_16x16x32_bf16(av[1][ti], bv[1][tj], acc[ti][tj], 0, 0, 0);
      }
    __syncthreads();   // vmcnt(0) drain lands AFTER the MFMA block -> prefetch overlapped
  }

  if (EPI == 1) {
#pragma unroll
    for (int ti = 0; ti < MT; ++ti)
#pragma unroll
      for (int tj = 0; tj < 4; ++tj)
#pragma unroll
        for (int r = 0; r < 4; ++r) {
          int m = m0 + wm * (MT * 16) + ti * 16 + q * 4 + r;
          int n = n0 + wn * 64 + tj * 16 + c;
          if (m < NF && n < NF) {
            float v = acc[ti][tj][r];
            int a = m / 23, b = m - a * 23;
            int y = n / 23, x = n - y * 23;
            int idx = (22 + y - a) * DMAP + (22 + x - b);
            float sw = spatialF[idx], lm = labelF[idx];
            float sa, msk;
            if (m == n) { sa = v; msk = 1.f; }
            else {
              sa = 0.5f * fabsf(v) + 0.5f * v;
              msk = (v > 0.f) ? 1.f : ((v < 0.f) ? 0.f : 0.5f);
            }
            float rv = msk * sw * sw * (sa - lm);
            size_t o = ((size_t)s * 640 + m) * NP + n;
            ush h = f2bf(rv);
            Rbh[o] = h;
            Rbl[o] = f2bf(rv - bf2f(h));
            Mb[((size_t)s * NF + m) * NP + n] = f2bf(msk);
          }
        }
  } else if (EPI == 2) {
    float reg = fmaxf(frp[0] * frp[0], 1e-10f);
#pragma unroll
    for (int ti = 0; ti < MT; ++ti) {
      float ps[4] = {0.f, 0.f, 0.f, 0.f};
      int mb = m0 + wm * (MT * 16) + ti * 16 + q * 4;
#pragma unroll
      for (int tj = 0; tj < 4; ++tj) {
        int n = n0 + wn * 64 + tj * 16 + c;
#pragma unroll
        for (int r = 0; r < 4; ++r) {
          int m = mb + r;
          if (m < NF) {
            float v = acc[ti][tj][r] + reg * F[((size_t)s * NF + m) * K9 + n];
            size_t o = ((size_t)s * 576 + m) * K9 + n;
            ush h = f2bf(v);
            FGh[o] = h;
            FGl[o] = f2bf(v - bf2f(h));
            ps[r] += v * v;
          }
        }
      }
#pragma unroll
      for (int r = 0; r < 4; ++r) {
        float p = ps[r];
        p += __shfl_xor(p, 1); p += __shfl_xor(p, 2);
        p += __shfl_xor(p, 4); p += __shfl_xor(p, 8);
        if (c == 0 && (mb + r) < NF) atomicAdd(&numb[s * NF + mb + r], p);
      }
    }
  } else {
#pragma unroll
    for (int ti = 0; ti < MT; ++ti) {
      float ps[4] = {0.f, 0.f, 0.f, 0.f};
      int mb = m0 + wm * (MT * 16) + ti * 16 + q * 4;
#pragma unroll
      for (int tj = 0; tj < 4; ++tj) {
        int n = n0 + wn * 64 + tj * 16 + c;
#pragma unroll
        for (int r = 0; r < 4; ++r) {
          int m = mb + r;
          if (m < NF && n < NF) {
            int a = m / 23, b = m - a * 23;
            int y = n / 23, x = n - y * 23;
            int idx = (22 + y - a) * DMAP + (22 + x - b);
            float sw = spatialF[idx];
            float msk = bf2f(Mb[((size_t)s * NF + m) * NP + n]);
            float z = sw * msk * acc[ti][tj][r];
            ps[r] += z * z;
          }
        }
      }
#pragma unroll
      for (int r = 0; r < 4; ++r) {
        float p = ps[r];
        p += __shfl_xor(p, 1); p += __shfl_xor(p, 2);
        p += __shfl_xor(p, 4); p += __shfl_xor(p, 8);
        if (c == 0 && (mb + r) < NF) atomicAdd(&denb[s * NF + mb + r], p);
      }
    }
  }
}

// ---------------- filter update (+ refresh hi/lo planes), 8 elems/thread ----------------
__global__ void update_f(float* __restrict__ F, const ush* __restrict__ FGh,
                         const ush* __restrict__ FGl,
                         const float* __restrict__ numb, const float* __restrict__ denb,
                         const float* __restrict__ lsp, const float* __restrict__ frp,
                         ush* __restrict__ Fh, ush* __restrict__ Fl) {
  int g = blockIdx.x * 256 + threadIdx.x;
  int row = g / 288;
  int kk = (g - row * 288) * 8;
  int s = row / NF, m = row - s * NF;
  float reg = fmaxf(frp[0] * frp[0], 1e-10f);
  float nm = numb[row], dn = denb[row];
  float alpha = nm / fmaxf(dn + reg * nm, 1e-8f);
  float sa = expf(lsp[0]) * alpha;
  size_t o = ((size_t)s * 576 + m) * K9 + kk;
  ush8 gh = *(const ush8*)(FGh + o);
  ush8 gl = *(const ush8*)(FGl + o);
  float4* Fp = (float4*)(F + (size_t)row * K9 + kk);
  float4 a = Fp[0], b = Fp[1];
  float f[8] = {a.x, a.y, a.z, a.w, b.x, b.y, b.z, b.w};
  ush8 h, lo;
#pragma unroll
  for (int i = 0; i < 8; ++i) {
    f[i] -= sa * (bf2f(gh[i]) + bf2f(gl[i]));
    ush hh = f2bf(f[i]);
    h[i] = hh;
    lo[i] = f2bf(f[i] - bf2f(hh));
  }
  Fp[0] = (float4){f[0], f[1], f[2], f[3]};
  Fp[1] = (float4){f[4], f[5], f[6], f[7]};
  *(ush8*)(Fh + o) = h;
  *(ush8*)(Fl + o) = lo;
}

// ---------------- driver ----------------
extern "C" void kernel_launch(void* const* d_in, const int* in_sizes, int n_in,
                              void* d_out, int out_size, void* d_ws, size_t ws_size,
                              hipStream_t stream) {
  const float* filt = (const float*)d_in[0];
  const float* feat = (const float*)d_in[1];
  const float* wl   = (const float*)d_in[2];
  const float* wsp  = (const float*)d_in[3];
  const float* lsp  = (const float*)d_in[4];
  const float* frp  = (const float*)d_in[5];
  float* F = (float*)d_out;

  float* fb       = (float*)d_ws;
  float* labelF   = fb;
  float* spatialF = fb + 2048;
  float* numden   = fb + 4096;             // [2 iters][num|den][4240]
  ush* cur = (ush*)(fb + 4096 + 4 * 4240);

  const size_t szF  = (size_t)8 * 576 * K9;    // 10,616,832
  const size_t szXT = (size_t)8 * 640 * K9;    // 11,796,480
  const size_t szXb = (size_t)8 * K9 * NP;     // 10,027,008
  const size_t szRb = (size_t)8 * 640 * NP;    //  2,785,280
  const size_t szMb = (size_t)8 * NF * NP;     //  2,302,208

  ush* Fh  = cur;            cur += szF;
  ush* Fl  = cur;            cur += szF;
  ush* XTh = cur;            cur += szXT;
  ush* XTl = cur;            cur += szXT;
  ush* Xbh = cur;            cur += szXb;
  ush* Xbl = cur;            cur += szXb;
  ush* Rbh = cur;            cur += szRb;
  ush* Rbl = cur;            cur += szRb;
  ush* Mb  = cur;            cur += szMb;
  ush* FGh = cur;            cur += szF;
  ush* FGl = cur;            cur += szF;
  // total ~188 MB

  build_maps<<<8, 256, 0, stream>>>(wl, wsp, labelF, spatialF);
  hipMemsetAsync(numden, 0, 4 * 4240 * sizeof(float), stream);
  convert_f<<<4761, 256, 0, stream>>>(filt, F, Fh, Fl);
  im2col_pack<<<dim3(10, 36, 8), 256, 0, stream>>>(feat, Xbh, Xbl, XTh, XTl);

  for (int it = 0; it < 2; ++it) {
    float* numb = numden + it * 2 * 4240;
    float* denb = numb + 4240;
    // scores (4-product split bf16, sign-exact) -> Rbh/Rbl, Mb
    gemm_mfma<64, 576, 640, K9, 2, 2, 1, 1><<<dim3(9, 5, 8), 256, 0, stream>>>(
        Fh, Fl, XTh, XTl, labelF, spatialF, Rbh, Rbl, Mb,
        nullptr, nullptr, nullptr, nullptr, nullptr, nullptr);
    // filter_grad = R*X^T + reg*F (3-product split) -> FGh/FGl + num
    gemm_mfma<128, 640, K9, NP, 2, 2, 0, 2><<<dim3(5, 18, 8), 256, 0, stream>>>(
        Rbh, Rbl, Xbh, Xbl, nullptr, nullptr, nullptr, nullptr, nullptr,
        F, frp, FGh, FGl, numb, nullptr);
    // scores_grad (2-product: A split, B hi) -> den
    gemm_mfma<64, 576, 640, K9, 2, 1, 0, 3><<<dim3(9, 5, 8), 256, 0, stream>>>(
        FGh, FGl, XTh, nullptr, nullptr, spatialF, nullptr, nullptr, Mb,
        nullptr, nullptr, nullptr, nullptr, nullptr, denb);
    update_f<<<4761, 256, 0, stream>>>(F, FGh, FGl, numb, denb, lsp, frp, Fh, Fl);
  }
}

// Round 6
// 730.674 us; speedup vs baseline: 1.9444x; 1.0748x over previous
//
#include <hip/hip_runtime.h>
#include <math.h>

#define NF   529
#define K9   2304
#define NP   544
#define DMAP 45

typedef unsigned short ush;
typedef unsigned int u32;
typedef __bf16 bf8_t __attribute__((ext_vector_type(8)));
typedef float f4_t __attribute__((ext_vector_type(4)));
typedef ush ush8 __attribute__((ext_vector_type(8)));

// Interleaved split layout: tensor[row][K/32][plane(hi,lo)][32] ush.
// Row stride = 2*K. 128B-contiguous per row per 32-K chunk (both planes).

__device__ __forceinline__ ush f2bf(float f) {
  union { float f; u32 u; } v; v.f = f;
  u32 r = v.u + 0x7fffu + ((v.u >> 16) & 1u);
  return (ush)(r >> 16);
}
__device__ __forceinline__ float bf2f(ush h) {
  union { u32 u; float f; } v; v.u = ((u32)h) << 16;
  return v.f;
}
__device__ __forceinline__ void async16(const void* g, void* l) {
  __builtin_amdgcn_global_load_lds((const __attribute__((address_space(1))) u32*)g,
                                   (__attribute__((address_space(3))) u32*)l, 16, 0, 0);
}

// ---------------- label / spatial map builder (45x45) ----------------
__global__ void build_maps(const float* __restrict__ wl, const float* __restrict__ wsp,
                           float* __restrict__ labelF, float* __restrict__ spatialF) {
  int idx = blockIdx.x * blockDim.x + threadIdx.x;
  if (idx >= DMAP * DMAP) return;
  int h = idx / DMAP, w = idx % DMAP;
  float dy = (float)(h - 22), dx = (float)(w - 22);
  float dist = sqrtf(dy * dy + dx * dx);
  float lab = 0.f, sp = 0.f;
#pragma unroll
  for (int b = 0; b < 9; ++b) {
    float bd = dist * 2.f - (float)b;
    float wt = fmaxf(0.f, 1.f - fabsf(bd));
    lab += wl[b] * wt;
    sp  += wsp[b] * wt;
  }
  float bd = dist * 2.f - 9.f;
  float wt = fminf(fmaxf(1.f + bd, 0.f), 1.f);
  lab += wl[9] * wt;
  sp  += wsp[9] * wt;
  labelF[idx] = lab;
  spatialF[idx] = sp;
}

// ---- convert filter -> fp32 copy (d_out) + interleaved hi/lo [s][576][2*2304] ----
__global__ void convert_f(const float* __restrict__ filt, float* __restrict__ F,
                          ush* __restrict__ Fhl) {
  int g = blockIdx.x * 256 + threadIdx.x;        // 4761 blocks
  int row = g / 288;
  int kk = (g - row * 288) * 8;
  int s = row / NF, m = row - s * NF;
  const float4* fp = (const float4*)(filt + (size_t)row * K9 + kk);
  float4 a = fp[0], b = fp[1];
  float4* Fp = (float4*)(F + (size_t)row * K9 + kk);
  Fp[0] = a; Fp[1] = b;
  float vv[8] = {a.x, a.y, a.z, a.w, b.x, b.y, b.z, b.w};
  ush8 h, lo;
#pragma unroll
  for (int i = 0; i < 8; ++i) {
    ush hh = f2bf(vv[i]);
    h[i] = hh;
    lo[i] = f2bf(vv[i] - bf2f(hh));
  }
  size_t o = ((size_t)s * 576 + m) * (2 * K9) + (kk >> 5) * 64 + (kk & 31);
  *(ush8*)(Fhl + o) = h;
  *(ush8*)(Fhl + o + 32) = lo;
}

// ---- im2col + pack: Xbhl[s][2304][2*544], XThl[s][640][2*2304] ----
__global__ void im2col_pack(const float* __restrict__ feat,
                            ush* __restrict__ Xbhl, ush* __restrict__ XThl) {
  __shared__ float T[64][65];
  int s = blockIdx.z, k0 = blockIdx.y * 64, yx0 = blockIdx.x * 64;
  int t = threadIdx.x;
  int r = t >> 2, c4 = (t & 3) * 16;
  int k = k0 + r;
  int ck = k / 9, j = k - ck * 9;
  int dy = j / 3 - 1, dx = j - (j / 3) * 3 - 1;
  const float* fb = feat + ((size_t)s * 256 + ck) * 529;
  float v[16];
#pragma unroll
  for (int i = 0; i < 16; ++i) {
    int yx = yx0 + c4 + i;
    float vv = 0.f;
    if (yx < NF) {
      int yy = yx / 23;
      int y = yy + dy, x = yx - yy * 23 + dx;
      if (y >= 0 && y < 23 && x >= 0 && x < 23) vv = fb[y * 23 + x];
    }
    v[i] = vv;
    T[r][c4 + i] = vv;
  }
  int c0 = yx0 + c4;
  if (c0 < NP) {
    size_t o = ((size_t)s * K9 + k) * (2 * NP) + (c0 >> 5) * 64 + (c0 & 31);
    ush8 h[2], lo[2];
#pragma unroll
    for (int gg = 0; gg < 2; ++gg)
#pragma unroll
      for (int i = 0; i < 8; ++i) {
        float vv = v[gg * 8 + i];
        ush hh = f2bf(vv);
        h[gg][i] = hh;
        lo[gg][i] = f2bf(vv - bf2f(hh));
      }
    *(ush8*)(Xbhl + o) = h[0];
    *(ush8*)(Xbhl + o + 8) = h[1];
    *(ush8*)(Xbhl + o + 32) = lo[0];
    *(ush8*)(Xbhl + o + 40) = lo[1];
  }
  __syncthreads();
  int kc = k0 + c4;
  size_t o2 = ((size_t)s * 640 + yx0 + r) * (2 * K9) + (kc >> 5) * 64 + (kc & 31);
  ush8 h2[2], l2[2];
#pragma unroll
  for (int gg = 0; gg < 2; ++gg)
#pragma unroll
    for (int i = 0; i < 8; ++i) {
      float vv = T[c4 + gg * 8 + i][r];
      ush hh = f2bf(vv);
      h2[gg][i] = hh;
      l2[gg][i] = f2bf(vv - bf2f(hh));
    }
  *(ush8*)(XThl + o2) = h2[0];
  *(ush8*)(XThl + o2 + 8) = h2[1];
  *(ush8*)(XThl + o2 + 32) = l2[0];
  *(ush8*)(XThl + o2 + 40) = l2[1];
}

// ---------------- MFMA GEMM, 256 thr, BN=128, BK=32, dbuf LDS, XCD swizzle ----
// EPI=1: scores -> Rbhl (split residuals) + Mb (mask)
// EPI=2: filter_grad (+reg*F) -> FGhl (split) + num (atomic row sumsq)
// EPI=3: scores_grad -> den (atomic row sum of (sw*mask*v)^2)
// SWZ=1: group blocks sharing B-strip (same y,s) on one XCD; SWZ=2: same x,s.
template <int BM, int AROWS, int BROWS, int KTOT, int ASPL, int BSPL, int FULL, int EPI,
          int SWZ, int GX, int GY>
__launch_bounds__(256, 2)
__global__ void gemm_mfma(const ush* __restrict__ Ahl, const ush* __restrict__ Bhl,
                          const float* __restrict__ labelF, const float* __restrict__ spatialF,
                          ush* __restrict__ Rbhl, ush* __restrict__ Mb,
                          const float* __restrict__ F, const float* __restrict__ frp,
                          ush* __restrict__ FGhl,
                          float* __restrict__ numb, float* __restrict__ denb) {
  constexpr int MT = BM / 32;
  constexpr int AI = BM / 64;
  constexpr int NCH = KTOT / 32;

  __shared__ ush As[2][ASPL][BM * 32];
  __shared__ ush Bs[2][BSPL][128 * 32];

  const int tid = threadIdx.x;
  const int w = tid >> 6, l = tid & 63;
  const int wm = w & 1, wn = w >> 1;
  const int q = l >> 4, c = l & 15;

  int x, y, s;
  {
    int bid = blockIdx.x;
    int xcd = bid & 7, t = bid >> 3;
    if (SWZ == 1) {
      int gi = t / GX; x = t - gi * GX;
      int g = gi * 8 + xcd; y = g % GY; s = g / GY;
    } else {
      int gi = t / GY; y = t - gi * GY;
      int g = gi * 8 + xcd; x = g % GX; s = g / GX;
    }
  }
  const int m0 = x * BM, n0 = y * 128;

  const ush* A0 = Ahl + (size_t)s * AROWS * (2 * KTOT);
  const ush* B0 = Bhl + (size_t)s * BROWS * (2 * KTOT);

  const int srow = w * 16 + (l >> 2);
  const int scol = (l & 3) * 8;     // within-32-plane segment

  auto stage = [&](int ch, int buf) {
    const int k2 = ch * 64;         // interleaved element offset for k0=ch*32
#pragma unroll
    for (int i = 0; i < AI; ++i) {
      size_t ro = (size_t)(m0 + i * 64 + srow) * (2 * KTOT) + k2 + scol;
      async16(A0 + ro, &As[buf][0][i * 2048 + w * 512]);
      if (ASPL == 2) async16(A0 + ro + 32, &As[buf][1][i * 2048 + w * 512]);
    }
#pragma unroll
    for (int i = 0; i < 2; ++i) {
      size_t ro = (size_t)(n0 + i * 64 + srow) * (2 * KTOT) + k2 + scol;
      async16(B0 + ro, &Bs[buf][0][i * 2048 + w * 512]);
      if (BSPL == 2) async16(B0 + ro + 32, &Bs[buf][1][i * 2048 + w * 512]);
    }
  };

  f4_t acc[MT][4];
#pragma unroll
  for (int i = 0; i < MT; ++i)
#pragma unroll
    for (int jj = 0; jj < 4; ++jj) acc[i][jj] = (f4_t){0.f, 0.f, 0.f, 0.f};

  stage(0, 0);
  __syncthreads();

  for (int ch = 0; ch < NCH; ++ch) {
    const int p = ch & 1;
    if (ch + 1 < NCH) stage(ch + 1, 1 - p);

    bf8_t av[ASPL][MT], bv[BSPL][4];
#pragma unroll
    for (int pp = 0; pp < ASPL; ++pp)
#pragma unroll
      for (int ti = 0; ti < MT; ++ti)
        av[pp][ti] = *(const bf8_t*)&As[p][pp][(wm * (MT * 16) + ti * 16 + c) * 32 + q * 8];
#pragma unroll
    for (int pp = 0; pp < BSPL; ++pp)
#pragma unroll
      for (int tj = 0; tj < 4; ++tj)
        bv[pp][tj] = *(const bf8_t*)&Bs[p][pp][(wn * 64 + tj * 16 + c) * 32 + q * 8];

#pragma unroll
    for (int ti = 0; ti < MT; ++ti)
#pragma unroll
      for (int tj = 0; tj < 4; ++tj) {
        acc[ti][tj] = __builtin_amdgcn_mfma_f32_16x16x32_bf16(av[0][ti], bv[0][tj], acc[ti][tj], 0, 0, 0);
        if (ASPL == 2)
          acc[ti][tj] = __builtin_amdgcn_mfma_f32_16x16x32_bf16(av[1][ti], bv[0][tj], acc[ti][tj], 0, 0, 0);
        if (BSPL == 2)
          acc[ti][tj] = __builtin_amdgcn_mfma_f32_16x16x32_bf16(av[0][ti], bv[1][tj], acc[ti][tj], 0, 0, 0);
        if (FULL)
          acc[ti][tj] = __builtin_amdgcn_mfma_f32_16x16x32_bf16(av[1][ti], bv[1][tj], acc[ti][tj], 0, 0, 0);
      }
    __syncthreads();
  }

  if (EPI == 1) {
#pragma unroll
    for (int ti = 0; ti < MT; ++ti)
#pragma unroll
      for (int tj = 0; tj < 4; ++tj)
#pragma unroll
        for (int r = 0; r < 4; ++r) {
          int m = m0 + wm * (MT * 16) + ti * 16 + q * 4 + r;
          int n = n0 + wn * 64 + tj * 16 + c;
          if (m < NF && n < NF) {
            float v = acc[ti][tj][r];
            int a = m / 23, b = m - a * 23;
            int yy = n / 23, xx = n - yy * 23;
            int idx = (22 + yy - a) * DMAP + (22 + xx - b);
            float sw = spatialF[idx], lm = labelF[idx];
            float sa, msk;
            if (m == n) { sa = v; msk = 1.f; }
            else {
              sa = 0.5f * fabsf(v) + 0.5f * v;
              msk = (v > 0.f) ? 1.f : ((v < 0.f) ? 0.f : 0.5f);
            }
            float rv = msk * sw * sw * (sa - lm);
            size_t o = ((size_t)s * 640 + m) * (2 * NP) + ((n >> 5) * 64) + (n & 31);
            ush h = f2bf(rv);
            Rbhl[o] = h;
            Rbhl[o + 32] = f2bf(rv - bf2f(h));
            Mb[((size_t)s * NF + m) * NP + n] = f2bf(msk);
          }
        }
  } else if (EPI == 2) {
    float reg = fmaxf(frp[0] * frp[0], 1e-10f);
#pragma unroll
    for (int ti = 0; ti < MT; ++ti) {
      float ps[4] = {0.f, 0.f, 0.f, 0.f};
      int mb = m0 + wm * (MT * 16) + ti * 16 + q * 4;
#pragma unroll
      for (int tj = 0; tj < 4; ++tj) {
        int n = n0 + wn * 64 + tj * 16 + c;
#pragma unroll
        for (int r = 0; r < 4; ++r) {
          int m = mb + r;
          if (m < NF) {
            float v = acc[ti][tj][r] + reg * F[((size_t)s * NF + m) * K9 + n];
            size_t o = ((size_t)s * 576 + m) * (2 * K9) + ((n >> 5) * 64) + (n & 31);
            ush h = f2bf(v);
            FGhl[o] = h;
            FGhl[o + 32] = f2bf(v - bf2f(h));
            ps[r] += v * v;
          }
        }
      }
#pragma unroll
      for (int r = 0; r < 4; ++r) {
        float p = ps[r];
        p += __shfl_xor(p, 1); p += __shfl_xor(p, 2);
        p += __shfl_xor(p, 4); p += __shfl_xor(p, 8);
        if (c == 0 && (mb + r) < NF) atomicAdd(&numb[s * NF + mb + r], p);
      }
    }
  } else {
#pragma unroll
    for (int ti = 0; ti < MT; ++ti) {
      float ps[4] = {0.f, 0.f, 0.f, 0.f};
      int mb = m0 + wm * (MT * 16) + ti * 16 + q * 4;
#pragma unroll
      for (int tj = 0; tj < 4; ++tj) {
        int n = n0 + wn * 64 + tj * 16 + c;
#pragma unroll
        for (int r = 0; r < 4; ++r) {
          int m = mb + r;
          if (m < NF && n < NF) {
            int a = m / 23, b = m - a * 23;
            int yy = n / 23, xx = n - yy * 23;
            int idx = (22 + yy - a) * DMAP + (22 + xx - b);
            float sw = spatialF[idx];
            float msk = bf2f(Mb[((size_t)s * NF + m) * NP + n]);
            float z = sw * msk * acc[ti][tj][r];
            ps[r] += z * z;
          }
        }
      }
#pragma unroll
      for (int r = 0; r < 4; ++r) {
        float p = ps[r];
        p += __shfl_xor(p, 1); p += __shfl_xor(p, 2);
        p += __shfl_xor(p, 4); p += __shfl_xor(p, 8);
        if (c == 0 && (mb + r) < NF) atomicAdd(&denb[s * NF + mb + r], p);
      }
    }
  }
}

// ---------------- filter update (+ refresh interleaved F planes) ----------------
__global__ void update_f(float* __restrict__ F, const ush* __restrict__ FGhl,
                         const float* __restrict__ numb, const float* __restrict__ denb,
                         const float* __restrict__ lsp, const float* __restrict__ frp,
                         ush* __restrict__ Fhl) {
  int g = blockIdx.x * 256 + threadIdx.x;
  int row = g / 288;
  int kk = (g - row * 288) * 8;
  int s = row / NF, m = row - s * NF;
  float reg = fmaxf(frp[0] * frp[0], 1e-10f);
  float nm = numb[row], dn = denb[row];
  float alpha = nm / fmaxf(dn + reg * nm, 1e-8f);
  float sa = expf(lsp[0]) * alpha;
  size_t o = ((size_t)s * 576 + m) * (2 * K9) + (kk >> 5) * 64 + (kk & 31);
  ush8 gh = *(const ush8*)(FGhl + o);
  ush8 gl = *(const ush8*)(FGhl + o + 32);
  float4* Fp = (float4*)(F + (size_t)row * K9 + kk);
  float4 a = Fp[0], b = Fp[1];
  float f[8] = {a.x, a.y, a.z, a.w, b.x, b.y, b.z, b.w};
  ush8 h, lo;
#pragma unroll
  for (int i = 0; i < 8; ++i) {
    f[i] -= sa * (bf2f(gh[i]) + bf2f(gl[i]));
    ush hh = f2bf(f[i]);
    h[i] = hh;
    lo[i] = f2bf(f[i] - bf2f(hh));
  }
  Fp[0] = (float4){f[0], f[1], f[2], f[3]};
  Fp[1] = (float4){f[4], f[5], f[6], f[7]};
  *(ush8*)(Fhl + o) = h;
  *(ush8*)(Fhl + o + 32) = lo;
}

// ---------------- driver ----------------
extern "C" void kernel_launch(void* const* d_in, const int* in_sizes, int n_in,
                              void* d_out, int out_size, void* d_ws, size_t ws_size,
                              hipStream_t stream) {
  const float* filt = (const float*)d_in[0];
  const float* feat = (const float*)d_in[1];
  const float* wl   = (const float*)d_in[2];
  const float* wsp  = (const float*)d_in[3];
  const float* lsp  = (const float*)d_in[4];
  const float* frp  = (const float*)d_in[5];
  float* F = (float*)d_out;

  float* fb       = (float*)d_ws;
  float* labelF   = fb;
  float* spatialF = fb + 2048;
  float* numden   = fb + 4096;             // [2 iters][num|den][4240]
  ush* cur = (ush*)(fb + 4096 + 4 * 4240);

  const size_t szF  = (size_t)8 * 576 * (2 * K9);   // 21,233,664
  const size_t szXT = (size_t)8 * 640 * (2 * K9);   // 23,592,960
  const size_t szXb = (size_t)8 * K9 * (2 * NP);    // 20,054,016
  const size_t szRb = (size_t)8 * 640 * (2 * NP);   //  5,570,560
  const size_t szMb = (size_t)8 * NF * NP;          //  2,302,208

  ush* Fhl  = cur;           cur += szF;
  ush* XThl = cur;           cur += szXT;
  ush* Xbhl = cur;           cur += szXb;
  ush* Rbhl = cur;           cur += szRb;
  ush* Mb   = cur;           cur += szMb;
  ush* FGhl = cur;           cur += szF;
  // total ~188 MB

  build_maps<<<8, 256, 0, stream>>>(wl, wsp, labelF, spatialF);
  hipMemsetAsync(numden, 0, 4 * 4240 * sizeof(float), stream);
  convert_f<<<4761, 256, 0, stream>>>(filt, F, Fhl);
  im2col_pack<<<dim3(10, 36, 8), 256, 0, stream>>>(feat, Xbhl, XThl);

  for (int it = 0; it < 2; ++it) {
    float* numb = numden + it * 2 * 4240;
    float* denb = numb + 4240;
    // scores (3-product split bf16, sign-safe) -> Rbhl, Mb
    gemm_mfma<64, 576, 640, K9, 2, 2, 0, 1, 1, 9, 5><<<360, 256, 0, stream>>>(
        Fhl, XThl, labelF, spatialF, Rbhl, Mb, nullptr, nullptr, nullptr, nullptr, nullptr);
    // filter_grad = R*X^T + reg*F (3-product) -> FGhl + num
    gemm_mfma<128, 640, K9, NP, 2, 2, 0, 2, 2, 5, 18><<<720, 256, 0, stream>>>(
        Rbhl, Xbhl, nullptr, nullptr, nullptr, nullptr, F, frp, FGhl, numb, nullptr);
    // scores_grad (2-product: A split, B hi) -> den
    gemm_mfma<64, 576, 640, K9, 2, 1, 0, 3, 1, 9, 5><<<360, 256, 0, stream>>>(
        FGhl, XThl, nullptr, spatialF, nullptr, Mb, nullptr, nullptr, nullptr, nullptr, denb);
    update_f<<<4761, 256, 0, stream>>>(F, FGhl, numb, denb, lsp, frp, Fhl);
  }
}

// Round 7
// 574.487 us; speedup vs baseline: 2.4730x; 1.2719x over previous
//
#include <hip/hip_runtime.h>
#include <math.h>

#define NF   529
#define K9   2304
#define NP   544
#define DMAP 45

typedef unsigned short ush;
typedef unsigned int u32;
typedef __bf16 bf8_t __attribute__((ext_vector_type(8)));
typedef float f4_t __attribute__((ext_vector_type(4)));
typedef ush ush8 __attribute__((ext_vector_type(8)));

// Interleaved split layout: tensor[row][K/32][plane(hi,lo)][32] ush. Row stride 2*K.

__device__ __forceinline__ ush f2bf(float f) {
  union { float f; u32 u; } v; v.f = f;
  u32 r = v.u + 0x7fffu + ((v.u >> 16) & 1u);
  return (ush)(r >> 16);
}
__device__ __forceinline__ float bf2f(ush h) {
  union { u32 u; float f; } v; v.u = ((u32)h) << 16;
  return v.f;
}
__device__ __forceinline__ void async16(const void* g, void* l) {
  __builtin_amdgcn_global_load_lds((const __attribute__((address_space(1))) u32*)g,
                                   (__attribute__((address_space(3))) u32*)l, 16, 0, 0);
}

// ---------------- label / spatial map builder (45x45) ----------------
__global__ void build_maps(const float* __restrict__ wl, const float* __restrict__ wsp,
                           float* __restrict__ labelF, float* __restrict__ spatialF) {
  int idx = blockIdx.x * blockDim.x + threadIdx.x;
  if (idx >= DMAP * DMAP) return;
  int h = idx / DMAP, w = idx % DMAP;
  float dy = (float)(h - 22), dx = (float)(w - 22);
  float dist = sqrtf(dy * dy + dx * dx);
  float lab = 0.f, sp = 0.f;
#pragma unroll
  for (int b = 0; b < 9; ++b) {
    float bd = dist * 2.f - (float)b;
    float wt = fmaxf(0.f, 1.f - fabsf(bd));
    lab += wl[b] * wt;
    sp  += wsp[b] * wt;
  }
  float bd = dist * 2.f - 9.f;
  float wt = fminf(fmaxf(1.f + bd, 0.f), 1.f);
  lab += wl[9] * wt;
  sp  += wsp[9] * wt;
  labelF[idx] = lab;
  spatialF[idx] = sp;
}

// ---- convert filter -> fp32 copy (d_out) + interleaved hi/lo [s][576][2*2304] ----
__global__ void convert_f(const float* __restrict__ filt, float* __restrict__ F,
                          ush* __restrict__ Fhl) {
  int g = blockIdx.x * 256 + threadIdx.x;        // 4761 blocks
  int row = g / 288;
  int kk = (g - row * 288) * 8;
  int s = row / NF, m = row - s * NF;
  const float4* fp = (const float4*)(filt + (size_t)row * K9 + kk);
  float4 a = fp[0], b = fp[1];
  float4* Fp = (float4*)(F + (size_t)row * K9 + kk);
  Fp[0] = a; Fp[1] = b;
  float vv[8] = {a.x, a.y, a.z, a.w, b.x, b.y, b.z, b.w};
  ush8 h, lo;
#pragma unroll
  for (int i = 0; i < 8; ++i) {
    ush hh = f2bf(vv[i]);
    h[i] = hh;
    lo[i] = f2bf(vv[i] - bf2f(hh));
  }
  size_t o = ((size_t)s * 576 + m) * (2 * K9) + (kk >> 5) * 64 + (kk & 31);
  *(ush8*)(Fhl + o) = h;
  *(ush8*)(Fhl + o + 32) = lo;
}

// ---- im2col + pack: Xbhl[s][2304][2*544], XThl[s][640][2*2304] ----
__global__ void im2col_pack(const float* __restrict__ feat,
                            ush* __restrict__ Xbhl, ush* __restrict__ XThl) {
  __shared__ float T[64][65];
  int s = blockIdx.z, k0 = blockIdx.y * 64, yx0 = blockIdx.x * 64;
  int t = threadIdx.x;
  int r = t >> 2, c4 = (t & 3) * 16;
  int k = k0 + r;
  int ck = k / 9, j = k - ck * 9;
  int dy = j / 3 - 1, dx = j - (j / 3) * 3 - 1;
  const float* fb = feat + ((size_t)s * 256 + ck) * 529;
  float v[16];
#pragma unroll
  for (int i = 0; i < 16; ++i) {
    int yx = yx0 + c4 + i;
    float vv = 0.f;
    if (yx < NF) {
      int yy = yx / 23;
      int y = yy + dy, x = yx - yy * 23 + dx;
      if (y >= 0 && y < 23 && x >= 0 && x < 23) vv = fb[y * 23 + x];
    }
    v[i] = vv;
    T[r][c4 + i] = vv;
  }
  int c0 = yx0 + c4;
  if (c0 < NP) {
    size_t o = ((size_t)s * K9 + k) * (2 * NP) + (c0 >> 5) * 64 + (c0 & 31);
    ush8 h[2], lo[2];
#pragma unroll
    for (int gg = 0; gg < 2; ++gg)
#pragma unroll
      for (int i = 0; i < 8; ++i) {
        float vv = v[gg * 8 + i];
        ush hh = f2bf(vv);
        h[gg][i] = hh;
        lo[gg][i] = f2bf(vv - bf2f(hh));
      }
    *(ush8*)(Xbhl + o) = h[0];
    *(ush8*)(Xbhl + o + 8) = h[1];
    *(ush8*)(Xbhl + o + 32) = lo[0];
    *(ush8*)(Xbhl + o + 40) = lo[1];
  }
  __syncthreads();
  int kc = k0 + c4;
  size_t o2 = ((size_t)s * 640 + yx0 + r) * (2 * K9) + (kc >> 5) * 64 + (kc & 31);
  ush8 h2[2], l2[2];
#pragma unroll
  for (int gg = 0; gg < 2; ++gg)
#pragma unroll
    for (int i = 0; i < 8; ++i) {
      float vv = T[c4 + gg * 8 + i][r];
      ush hh = f2bf(vv);
      h2[gg][i] = hh;
      l2[gg][i] = f2bf(vv - bf2f(hh));
    }
  *(ush8*)(XThl + o2) = h2[0];
  *(ush8*)(XThl + o2 + 8) = h2[1];
  *(ush8*)(XThl + o2 + 32) = l2[0];
  *(ush8*)(XThl + o2 + 40) = l2[1];
}

// ---------------- MFMA GEMM, single-buffer LDS (24KB -> ~6 blocks/CU), split-K ----
// BM=64, BN=128. MODE=0: write fp32 partials Cp[sk*8+s][576][640].
// MODE=2: filter_grad epilogue (+reg*F -> FGhl split, num atomicAdd).
// Block decode: p=bid%(8*SK) -> (s,sk) pinned to XCD p%8; j=bid/(8*SK) -> (x,y).
template <int AROWS, int BROWS, int KTOT, int ASPL, int BSPL, int FULL, int MODE,
          int GX, int SK, int CH>
__launch_bounds__(256, 2)
__global__ void gemm_sb(const ush* __restrict__ Ahl, const ush* __restrict__ Bhl,
                        float* __restrict__ Cp,
                        const float* __restrict__ F, const float* __restrict__ frp,
                        ush* __restrict__ FGhl, float* __restrict__ numb) {
  __shared__ ush As[ASPL][64 * 32];
  __shared__ ush Bs[BSPL][128 * 32];

  const int tid = threadIdx.x;
  const int w = tid >> 6, l = tid & 63;
  const int wm = w & 1, wn = w >> 1;
  const int q = l >> 4, c = l & 15;

  const int PC = 8 * SK;
  int p = blockIdx.x % PC;
  int j = blockIdx.x / PC;
  const int s = p / SK, sk = p % SK;
  const int x = j % GX, y = j / GX;
  const int m0 = x * 64, n0 = y * 128;

  const ush* A0 = Ahl + (size_t)s * AROWS * (2 * KTOT);
  const ush* B0 = Bhl + (size_t)s * BROWS * (2 * KTOT);

  const int srow = w * 16 + (l >> 2);
  const int scol = (l & 3) * 8;

  f4_t acc[2][4];
#pragma unroll
  for (int i = 0; i < 2; ++i)
#pragma unroll
    for (int jj = 0; jj < 4; ++jj) acc[i][jj] = (f4_t){0.f, 0.f, 0.f, 0.f};

  for (int ch = 0; ch < CH; ++ch) {
    const int k2 = (sk * CH + ch) * 64;
    {
      size_t ro = (size_t)(m0 + srow) * (2 * KTOT) + k2 + scol;
      async16(A0 + ro, &As[0][srow * 32 + scol]);
      if (ASPL == 2) async16(A0 + ro + 32, &As[1][srow * 32 + scol]);
    }
#pragma unroll
    for (int i = 0; i < 2; ++i) {
      size_t ro = (size_t)(n0 + i * 64 + srow) * (2 * KTOT) + k2 + scol;
      async16(B0 + ro, &Bs[0][i * 2048 + srow * 32 + scol]);
      if (BSPL == 2) async16(B0 + ro + 32, &Bs[1][i * 2048 + srow * 32 + scol]);
    }
    __syncthreads();

    bf8_t av[ASPL][2], bv[BSPL][4];
#pragma unroll
    for (int pp = 0; pp < ASPL; ++pp)
#pragma unroll
      for (int ti = 0; ti < 2; ++ti)
        av[pp][ti] = *(const bf8_t*)&As[pp][(wm * 32 + ti * 16 + c) * 32 + q * 8];
#pragma unroll
    for (int pp = 0; pp < BSPL; ++pp)
#pragma unroll
      for (int tj = 0; tj < 4; ++tj)
        bv[pp][tj] = *(const bf8_t*)&Bs[pp][(wn * 64 + tj * 16 + c) * 32 + q * 8];

#pragma unroll
    for (int ti = 0; ti < 2; ++ti)
#pragma unroll
      for (int tj = 0; tj < 4; ++tj) {
        acc[ti][tj] = __builtin_amdgcn_mfma_f32_16x16x32_bf16(av[0][ti], bv[0][tj], acc[ti][tj], 0, 0, 0);
        if (ASPL == 2)
          acc[ti][tj] = __builtin_amdgcn_mfma_f32_16x16x32_bf16(av[1][ti], bv[0][tj], acc[ti][tj], 0, 0, 0);
        if (BSPL == 2)
          acc[ti][tj] = __builtin_amdgcn_mfma_f32_16x16x32_bf16(av[0][ti], bv[1][tj], acc[ti][tj], 0, 0, 0);
        if (FULL)
          acc[ti][tj] = __builtin_amdgcn_mfma_f32_16x16x32_bf16(av[1][ti], bv[1][tj], acc[ti][tj], 0, 0, 0);
      }
    __syncthreads();
  }

  if (MODE == 0) {
    float* C = Cp + ((size_t)(sk * 8 + s) * 576) * 640;
#pragma unroll
    for (int ti = 0; ti < 2; ++ti)
#pragma unroll
      for (int tj = 0; tj < 4; ++tj)
#pragma unroll
        for (int r = 0; r < 4; ++r) {
          int m = m0 + wm * 32 + ti * 16 + q * 4 + r;
          int n = n0 + wn * 64 + tj * 16 + c;
          C[(size_t)m * 640 + n] = acc[ti][tj][r];
        }
  } else {
    float reg = fmaxf(frp[0] * frp[0], 1e-10f);
#pragma unroll
    for (int ti = 0; ti < 2; ++ti) {
      float ps[4] = {0.f, 0.f, 0.f, 0.f};
      int mb = m0 + wm * 32 + ti * 16 + q * 4;
#pragma unroll
      for (int tj = 0; tj < 4; ++tj) {
        int n = n0 + wn * 64 + tj * 16 + c;
#pragma unroll
        for (int r = 0; r < 4; ++r) {
          int m = mb + r;
          if (m < NF) {
            float v = acc[ti][tj][r] + reg * F[((size_t)s * NF + m) * K9 + n];
            size_t o = ((size_t)s * 576 + m) * (2 * K9) + ((n >> 5) * 64) + (n & 31);
            FGhl[o] = f2bf(v);
            FGhl[o + 32] = f2bf(v - bf2f(f2bf(v)));
            ps[r] += v * v;
          }
        }
      }
#pragma unroll
      for (int r = 0; r < 4; ++r) {
        float pp = ps[r];
        pp += __shfl_xor(pp, 1); pp += __shfl_xor(pp, 2);
        pp += __shfl_xor(pp, 4); pp += __shfl_xor(pp, 8);
        if (c == 0 && (mb + r) < NF) atomicAdd(&numb[s * NF + mb + r], pp);
      }
    }
  }
}

// ---- reduce partials (SK=4) + scores epilogue -> Rbhl, Mb. one block per (s,m) row ----
__global__ void reduce_epi1(const float* __restrict__ Cp,
                            const float* __restrict__ labelF, const float* __restrict__ spatialF,
                            ush* __restrict__ Rbhl, ush* __restrict__ Mb) {
  int row = blockIdx.x;             // 8*529
  int s = row / NF, m = row - s * NF;
  int a = m / 23, b = m - a * 23;
  const size_t sp = (size_t)8 * 576 * 640;
  const float* C = Cp + ((size_t)s * 576 + m) * 640;
  for (int n = threadIdx.x; n < NF; n += 256) {
    float v = C[n] + C[sp + n] + C[2 * sp + n] + C[3 * sp + n];
    int yy = n / 23, xx = n - yy * 23;
    int idx = (22 + yy - a) * DMAP + (22 + xx - b);
    float sw = spatialF[idx], lm = labelF[idx];
    float sa, msk;
    if (m == n) { sa = v; msk = 1.f; }
    else {
      sa = 0.5f * fabsf(v) + 0.5f * v;
      msk = (v > 0.f) ? 1.f : ((v < 0.f) ? 0.f : 0.5f);
    }
    float rv = msk * sw * sw * (sa - lm);
    size_t o = ((size_t)s * 640 + m) * (2 * NP) + ((n >> 5) * 64) + (n & 31);
    ush h = f2bf(rv);
    Rbhl[o] = h;
    Rbhl[o + 32] = f2bf(rv - bf2f(h));
    Mb[((size_t)s * NF + m) * NP + n] = f2bf(msk);
  }
}

// ---- reduce partials (SK=4) + den row-sum (deterministic, no atomics) ----
__global__ void reduce_epi3(const float* __restrict__ Cp,
                            const float* __restrict__ spatialF, const ush* __restrict__ Mb,
                            float* __restrict__ denb) {
  int row = blockIdx.x;             // 8*529
  int s = row / NF, m = row - s * NF;
  int a = m / 23, b = m - a * 23;
  const size_t sp = (size_t)8 * 576 * 640;
  const float* C = Cp + ((size_t)s * 576 + m) * 640;
  float ss = 0.f;
  for (int n = threadIdx.x; n < NF; n += 256) {
    float v = C[n] + C[sp + n] + C[2 * sp + n] + C[3 * sp + n];
    int yy = n / 23, xx = n - yy * 23;
    int idx = (22 + yy - a) * DMAP + (22 + xx - b);
    float sw = spatialF[idx];
    float msk = bf2f(Mb[((size_t)s * NF + m) * NP + n]);
    float z = sw * msk * v;
    ss += z * z;
  }
  __shared__ float red[256];
  red[threadIdx.x] = ss; __syncthreads();
  for (int st = 128; st > 0; st >>= 1) {
    if (threadIdx.x < st) red[threadIdx.x] += red[threadIdx.x + st];
    __syncthreads();
  }
  if (threadIdx.x == 0) denb[row] = red[0];
}

// ---------------- filter update (+ refresh interleaved F planes) ----------------
__global__ void update_f(float* __restrict__ F, const ush* __restrict__ FGhl,
                         const float* __restrict__ numb, const float* __restrict__ denb,
                         const float* __restrict__ lsp, const float* __restrict__ frp,
                         ush* __restrict__ Fhl) {
  int g = blockIdx.x * 256 + threadIdx.x;
  int row = g / 288;
  int kk = (g - row * 288) * 8;
  int s = row / NF, m = row - s * NF;
  float reg = fmaxf(frp[0] * frp[0], 1e-10f);
  float nm = numb[row], dn = denb[row];
  float alpha = nm / fmaxf(dn + reg * nm, 1e-8f);
  float sa = expf(lsp[0]) * alpha;
  size_t o = ((size_t)s * 576 + m) * (2 * K9) + (kk >> 5) * 64 + (kk & 31);
  ush8 gh = *(const ush8*)(FGhl + o);
  ush8 gl = *(const ush8*)(FGhl + o + 32);
  float4* Fp = (float4*)(F + (size_t)row * K9 + kk);
  float4 a = Fp[0], b = Fp[1];
  float f[8] = {a.x, a.y, a.z, a.w, b.x, b.y, b.z, b.w};
  ush8 h, lo;
#pragma unroll
  for (int i = 0; i < 8; ++i) {
    f[i] -= sa * (bf2f(gh[i]) + bf2f(gl[i]));
    ush hh = f2bf(f[i]);
    h[i] = hh;
    lo[i] = f2bf(f[i] - bf2f(hh));
  }
  Fp[0] = (float4){f[0], f[1], f[2], f[3]};
  Fp[1] = (float4){f[4], f[5], f[6], f[7]};
  *(ush8*)(Fhl + o) = h;
  *(ush8*)(Fhl + o + 32) = lo;
}

// ---------------- driver ----------------
extern "C" void kernel_launch(void* const* d_in, const int* in_sizes, int n_in,
                              void* d_out, int out_size, void* d_ws, size_t ws_size,
                              hipStream_t stream) {
  const float* filt = (const float*)d_in[0];
  const float* feat = (const float*)d_in[1];
  const float* wl   = (const float*)d_in[2];
  const float* wsp  = (const float*)d_in[3];
  const float* lsp  = (const float*)d_in[4];
  const float* frp  = (const float*)d_in[5];
  float* F = (float*)d_out;

  float* fb       = (float*)d_ws;
  float* labelF   = fb;
  float* spatialF = fb + 2048;
  float* numden   = fb + 4096;             // [2 iters][num|den][4240]
  float* Cp       = fb + 4096 + 4 * 4240;  // 4*8*576*640 fp32 = 47.2 MB
  ush* cur = (ush*)(Cp + (size_t)4 * 8 * 576 * 640);

  const size_t szF  = (size_t)8 * 576 * (2 * K9);   // 21,233,664
  const size_t szXT = (size_t)8 * 640 * (2 * K9);   // 23,592,960
  const size_t szXb = (size_t)8 * K9 * (2 * NP);    // 20,054,016
  const size_t szRb = (size_t)8 * 640 * (2 * NP);   //  5,570,560
  const size_t szMb = (size_t)8 * NF * NP;          //  2,302,208

  ush* Fhl  = cur;           cur += szF;
  ush* XThl = cur;           cur += szXT;
  ush* Xbhl = cur;           cur += szXb;
  ush* Rbhl = cur;           cur += szRb;
  ush* Mb   = cur;           cur += szMb;
  ush* FGhl = cur;           cur += szF;
  // total ~236 MB of ws

  build_maps<<<8, 256, 0, stream>>>(wl, wsp, labelF, spatialF);
  hipMemsetAsync(numden, 0, 4 * 4240 * sizeof(float), stream);
  convert_f<<<4761, 256, 0, stream>>>(filt, F, Fhl);
  im2col_pack<<<dim3(10, 36, 8), 256, 0, stream>>>(feat, Xbhl, XThl);

  for (int it = 0; it < 2; ++it) {
    float* numb = numden + it * 2 * 4240;
    float* denb = numb + 4240;
    // scores partials (3-product split bf16), SK=4 -> Cp
    gemm_sb<576, 640, K9, 2, 2, 0, 0, 9, 4, 18><<<1440, 256, 0, stream>>>(
        Fhl, XThl, Cp, nullptr, nullptr, nullptr, nullptr);
    reduce_epi1<<<8 * NF, 256, 0, stream>>>(Cp, labelF, spatialF, Rbhl, Mb);
    // filter_grad = R*X^T + reg*F (3-product) -> FGhl + num, direct (K=544)
    gemm_sb<640, K9, NP, 2, 2, 0, 2, 10, 1, 17><<<1440, 256, 0, stream>>>(
        Rbhl, Xbhl, nullptr, F, frp, FGhl, numb);
    // scores_grad partials (2-product: A split, B hi), SK=4 -> Cp
    gemm_sb<576, 640, K9, 2, 1, 0, 0, 9, 4, 18><<<1440, 256, 0, stream>>>(
        FGhl, XThl, Cp, nullptr, nullptr, nullptr, nullptr);
    reduce_epi3<<<8 * NF, 256, 0, stream>>>(Cp, spatialF, Mb, denb);
    update_f<<<4761, 256, 0, stream>>>(F, FGhl, numb, denb, lsp, frp, Fhl);
  }
}

// Round 8
// 550.356 us; speedup vs baseline: 2.5815x; 1.0438x over previous
//
#include <hip/hip_runtime.h>
#include <math.h>

#define NF   529
#define K9   2304
#define NP   544
#define DMAP 45

typedef unsigned short ush;
typedef unsigned int u32;
typedef __bf16 bf8_t __attribute__((ext_vector_type(8)));
typedef float f4_t __attribute__((ext_vector_type(4)));
typedef ush ush8 __attribute__((ext_vector_type(8)));

// Interleaved split layout: tensor[row][K/32][plane(hi,lo)][32] ush. Row stride 2*K.

__device__ __forceinline__ ush f2bf(float f) {
  union { float f; u32 u; } v; v.f = f;
  u32 r = v.u + 0x7fffu + ((v.u >> 16) & 1u);
  return (ush)(r >> 16);
}
__device__ __forceinline__ float bf2f(ush h) {
  union { u32 u; float f; } v; v.u = ((u32)h) << 16;
  return v.f;
}
__device__ __forceinline__ void async16(const void* g, void* l) {
  __builtin_amdgcn_global_load_lds((const __attribute__((address_space(1))) u32*)g,
                                   (__attribute__((address_space(3))) u32*)l, 16, 0, 0);
}

// ---------------- label / spatial map builder (45x45) ----------------
__global__ void build_maps(const float* __restrict__ wl, const float* __restrict__ wsp,
                           float* __restrict__ labelF, float* __restrict__ spatialF) {
  int idx = blockIdx.x * blockDim.x + threadIdx.x;
  if (idx >= DMAP * DMAP) return;
  int h = idx / DMAP, w = idx % DMAP;
  float dy = (float)(h - 22), dx = (float)(w - 22);
  float dist = sqrtf(dy * dy + dx * dx);
  float lab = 0.f, sp = 0.f;
#pragma unroll
  for (int b = 0; b < 9; ++b) {
    float bd = dist * 2.f - (float)b;
    float wt = fmaxf(0.f, 1.f - fabsf(bd));
    lab += wl[b] * wt;
    sp  += wsp[b] * wt;
  }
  float bd = dist * 2.f - 9.f;
  float wt = fminf(fmaxf(1.f + bd, 0.f), 1.f);
  lab += wl[9] * wt;
  sp  += wsp[9] * wt;
  labelF[idx] = lab;
  spatialF[idx] = sp;
}

// ---- convert filter -> fp32 copy (d_out) + interleaved hi/lo [s][576][2*2304] ----
__global__ void convert_f(const float* __restrict__ filt, float* __restrict__ F,
                          ush* __restrict__ Fhl) {
  int g = blockIdx.x * 256 + threadIdx.x;        // 4761 blocks
  int row = g / 288;
  int kk = (g - row * 288) * 8;
  int s = row / NF, m = row - s * NF;
  const float4* fp = (const float4*)(filt + (size_t)row * K9 + kk);
  float4 a = fp[0], b = fp[1];
  float4* Fp = (float4*)(F + (size_t)row * K9 + kk);
  Fp[0] = a; Fp[1] = b;
  float vv[8] = {a.x, a.y, a.z, a.w, b.x, b.y, b.z, b.w};
  ush8 h, lo;
#pragma unroll
  for (int i = 0; i < 8; ++i) {
    ush hh = f2bf(vv[i]);
    h[i] = hh;
    lo[i] = f2bf(vv[i] - bf2f(hh));
  }
  size_t o = ((size_t)s * 576 + m) * (2 * K9) + (kk >> 5) * 64 + (kk & 31);
  *(ush8*)(Fhl + o) = h;
  *(ush8*)(Fhl + o + 32) = lo;
}

// ---- im2col + pack: Xbhl[s][2304][2*544], XThl[s][640][2*2304] ----
__global__ void im2col_pack(const float* __restrict__ feat,
                            ush* __restrict__ Xbhl, ush* __restrict__ XThl) {
  __shared__ float T[64][65];
  int s = blockIdx.z, k0 = blockIdx.y * 64, yx0 = blockIdx.x * 64;
  int t = threadIdx.x;
  int r = t >> 2, c4 = (t & 3) * 16;
  int k = k0 + r;
  int ck = k / 9, j = k - ck * 9;
  int dy = j / 3 - 1, dx = j - (j / 3) * 3 - 1;
  const float* fb = feat + ((size_t)s * 256 + ck) * 529;
  float v[16];
#pragma unroll
  for (int i = 0; i < 16; ++i) {
    int yx = yx0 + c4 + i;
    float vv = 0.f;
    if (yx < NF) {
      int yy = yx / 23;
      int y = yy + dy, x = yx - yy * 23 + dx;
      if (y >= 0 && y < 23 && x >= 0 && x < 23) vv = fb[y * 23 + x];
    }
    v[i] = vv;
    T[r][c4 + i] = vv;
  }
  int c0 = yx0 + c4;
  if (c0 < NP) {
    size_t o = ((size_t)s * K9 + k) * (2 * NP) + (c0 >> 5) * 64 + (c0 & 31);
    ush8 h[2], lo[2];
#pragma unroll
    for (int gg = 0; gg < 2; ++gg)
#pragma unroll
      for (int i = 0; i < 8; ++i) {
        float vv = v[gg * 8 + i];
        ush hh = f2bf(vv);
        h[gg][i] = hh;
        lo[gg][i] = f2bf(vv - bf2f(hh));
      }
    *(ush8*)(Xbhl + o) = h[0];
    *(ush8*)(Xbhl + o + 8) = h[1];
    *(ush8*)(Xbhl + o + 32) = lo[0];
    *(ush8*)(Xbhl + o + 40) = lo[1];
  }
  __syncthreads();
  int kc = k0 + c4;
  size_t o2 = ((size_t)s * 640 + yx0 + r) * (2 * K9) + (kc >> 5) * 64 + (kc & 31);
  ush8 h2[2], l2[2];
#pragma unroll
  for (int gg = 0; gg < 2; ++gg)
#pragma unroll
    for (int i = 0; i < 8; ++i) {
      float vv = T[c4 + gg * 8 + i][r];
      ush hh = f2bf(vv);
      h2[gg][i] = hh;
      l2[gg][i] = f2bf(vv - bf2f(hh));
    }
  *(ush8*)(XThl + o2) = h2[0];
  *(ush8*)(XThl + o2 + 8) = h2[1];
  *(ush8*)(XThl + o2 + 32) = l2[0];
  *(ush8*)(XThl + o2 + 40) = l2[1];
}

// ------------- MFMA GEMM, 128x128 tile, single-buffer LDS, sequential XCD groups -------------
// Block decode: xcd=bid%8, t=bid/8, group g = xcd + 8*(t/BPG) -> one group active per XCD
// at a time (L2-resident working set). g -> (s = g/SKC, sk = g%SKC); j=t%BPG -> (x=j%GX, y=j/GX).
// MODE=0: fp32 partials Cp[sk*8+s][640][640].  MODE=2: filter_grad epilogue (+reg*F, num).
template <int KTOT, int ASPL, int BSPL, int MODE, int SKC, int CH, int BPG, int GX>
__launch_bounds__(256, 3)
__global__ void gemm128(const ush* __restrict__ Ahl, const ush* __restrict__ Bhl,
                        float* __restrict__ Cp,
                        const float* __restrict__ F, const float* __restrict__ frp,
                        ush* __restrict__ FGhl, float* __restrict__ numb,
                        const int arows) {
  __shared__ ush As[ASPL][128 * 32];
  __shared__ ush Bs[BSPL][128 * 32];

  const int tid = threadIdx.x;
  const int w = tid >> 6, l = tid & 63;
  const int wm = w & 1, wn = w >> 1;
  const int q = l >> 4, c = l & 15;

  const int xcd = blockIdx.x & 7;
  const int t = blockIdx.x >> 3;
  const int g = xcd + 8 * (t / BPG);
  const int j = t % BPG;
  const int s = g / SKC, sk = g % SKC;
  const int x = j % GX, y = j / GX;
  const int m0 = x * 128, n0 = y * 128;

  const ush* A0 = Ahl + (size_t)s * arows * (2 * KTOT);
  const ush* B0 = Bhl + (size_t)s * ((MODE == 2) ? K9 : 640) * (2 * KTOT);

  const int srow = w * 16 + (l >> 2);   // 0..63
  const int scol = (l & 3) * 8;

  f4_t acc[4][4];
#pragma unroll
  for (int i = 0; i < 4; ++i)
#pragma unroll
    for (int jj = 0; jj < 4; ++jj) acc[i][jj] = (f4_t){0.f, 0.f, 0.f, 0.f};

  for (int ch = 0; ch < CH; ++ch) {
    const int k2 = (sk * CH + ch) * 64;
#pragma unroll
    for (int i = 0; i < 2; ++i) {
      size_t ro = (size_t)(m0 + i * 64 + srow) * (2 * KTOT) + k2 + scol;
      async16(A0 + ro, &As[0][(i * 64 + srow) * 32 + scol]);
      if (ASPL == 2) async16(A0 + ro + 32, &As[1][(i * 64 + srow) * 32 + scol]);
    }
#pragma unroll
    for (int i = 0; i < 2; ++i) {
      size_t ro = (size_t)(n0 + i * 64 + srow) * (2 * KTOT) + k2 + scol;
      async16(B0 + ro, &Bs[0][(i * 64 + srow) * 32 + scol]);
      if (BSPL == 2) async16(B0 + ro + 32, &Bs[1][(i * 64 + srow) * 32 + scol]);
    }
    __syncthreads();

    bf8_t av[ASPL][4], bv[BSPL][4];
#pragma unroll
    for (int pp = 0; pp < ASPL; ++pp)
#pragma unroll
      for (int ti = 0; ti < 4; ++ti)
        av[pp][ti] = *(const bf8_t*)&As[pp][(wm * 64 + ti * 16 + c) * 32 + q * 8];
#pragma unroll
    for (int pp = 0; pp < BSPL; ++pp)
#pragma unroll
      for (int tj = 0; tj < 4; ++tj)
        bv[pp][tj] = *(const bf8_t*)&Bs[pp][(wn * 64 + tj * 16 + c) * 32 + q * 8];

#pragma unroll
    for (int ti = 0; ti < 4; ++ti)
#pragma unroll
      for (int tj = 0; tj < 4; ++tj) {
        acc[ti][tj] = __builtin_amdgcn_mfma_f32_16x16x32_bf16(av[0][ti], bv[0][tj], acc[ti][tj], 0, 0, 0);
        if (ASPL == 2)
          acc[ti][tj] = __builtin_amdgcn_mfma_f32_16x16x32_bf16(av[1][ti], bv[0][tj], acc[ti][tj], 0, 0, 0);
        if (BSPL == 2)
          acc[ti][tj] = __builtin_amdgcn_mfma_f32_16x16x32_bf16(av[0][ti], bv[1][tj], acc[ti][tj], 0, 0, 0);
      }
    __syncthreads();
  }

  if (MODE == 0) {
    float* C = Cp + (size_t)(sk * 8 + s) * 640 * 640;
#pragma unroll
    for (int ti = 0; ti < 4; ++ti)
#pragma unroll
      for (int tj = 0; tj < 4; ++tj)
#pragma unroll
        for (int r = 0; r < 4; ++r) {
          int m = m0 + wm * 64 + ti * 16 + q * 4 + r;
          int n = n0 + wn * 64 + tj * 16 + c;
          C[(size_t)m * 640 + n] = acc[ti][tj][r];
        }
  } else {
    float reg = fmaxf(frp[0] * frp[0], 1e-10f);
#pragma unroll
    for (int ti = 0; ti < 4; ++ti) {
      float ps[4] = {0.f, 0.f, 0.f, 0.f};
      int mb = m0 + wm * 64 + ti * 16 + q * 4;
#pragma unroll
      for (int tj = 0; tj < 4; ++tj) {
        int n = n0 + wn * 64 + tj * 16 + c;
#pragma unroll
        for (int r = 0; r < 4; ++r) {
          int m = mb + r;
          if (m < NF) {
            float v = acc[ti][tj][r] + reg * F[((size_t)s * NF + m) * K9 + n];
            size_t o = ((size_t)s * 576 + m) * (2 * K9) + ((n >> 5) * 64) + (n & 31);
            ush h = f2bf(v);
            FGhl[o] = h;
            FGhl[o + 32] = f2bf(v - bf2f(h));
            ps[r] += v * v;
          }
        }
      }
#pragma unroll
      for (int r = 0; r < 4; ++r) {
        float pp = ps[r];
        pp += __shfl_xor(pp, 1); pp += __shfl_xor(pp, 2);
        pp += __shfl_xor(pp, 4); pp += __shfl_xor(pp, 8);
        if (c == 0 && (mb + r) < NF) atomicAdd(&numb[s * NF + mb + r], pp);
      }
    }
  }
}

// ---- reduce partials (SK=4) + scores epilogue -> Rbhl, Mb. one block per (s,m) row ----
__global__ void reduce_epi1(const float* __restrict__ Cp,
                            const float* __restrict__ labelF, const float* __restrict__ spatialF,
                            ush* __restrict__ Rbhl, ush* __restrict__ Mb) {
  int row = blockIdx.x;             // 8*529
  int s = row / NF, m = row - s * NF;
  int a = m / 23, b = m - a * 23;
  const size_t sp = (size_t)8 * 640 * 640;
  const float* C = Cp + ((size_t)s * 640 + m) * 640;
  for (int n = threadIdx.x; n < NF; n += 256) {
    float v = C[n] + C[sp + n] + C[2 * sp + n] + C[3 * sp + n];
    int yy = n / 23, xx = n - yy * 23;
    int idx = (22 + yy - a) * DMAP + (22 + xx - b);
    float sw = spatialF[idx], lm = labelF[idx];
    float sa, msk;
    if (m == n) { sa = v; msk = 1.f; }
    else {
      sa = 0.5f * fabsf(v) + 0.5f * v;
      msk = (v > 0.f) ? 1.f : ((v < 0.f) ? 0.f : 0.5f);
    }
    float rv = msk * sw * sw * (sa - lm);
    size_t o = ((size_t)s * 640 + m) * (2 * NP) + ((n >> 5) * 64) + (n & 31);
    ush h = f2bf(rv);
    Rbhl[o] = h;
    Rbhl[o + 32] = f2bf(rv - bf2f(h));
    Mb[((size_t)s * NF + m) * NP + n] = f2bf(msk);
  }
}

// ---- reduce partials (SK=4) + den row-sum (deterministic, no atomics) ----
__global__ void reduce_epi3(const float* __restrict__ Cp,
                            const float* __restrict__ spatialF, const ush* __restrict__ Mb,
                            float* __restrict__ denb) {
  int row = blockIdx.x;             // 8*529
  int s = row / NF, m = row - s * NF;
  int a = m / 23, b = m - a * 23;
  const size_t sp = (size_t)8 * 640 * 640;
  const float* C = Cp + ((size_t)s * 640 + m) * 640;
  float ss = 0.f;
  for (int n = threadIdx.x; n < NF; n += 256) {
    float v = C[n] + C[sp + n] + C[2 * sp + n] + C[3 * sp + n];
    int yy = n / 23, xx = n - yy * 23;
    int idx = (22 + yy - a) * DMAP + (22 + xx - b);
    float sw = spatialF[idx];
    float msk = bf2f(Mb[((size_t)s * NF + m) * NP + n]);
    float z = sw * msk * v;
    ss += z * z;
  }
  __shared__ float red[256];
  red[threadIdx.x] = ss; __syncthreads();
  for (int st = 128; st > 0; st >>= 1) {
    if (threadIdx.x < st) red[threadIdx.x] += red[threadIdx.x + st];
    __syncthreads();
  }
  if (threadIdx.x == 0) denb[row] = red[0];
}

// ---------------- filter update (+ refresh interleaved F planes) ----------------
__global__ void update_f(float* __restrict__ F, const ush* __restrict__ FGhl,
                         const float* __restrict__ numb, const float* __restrict__ denb,
                         const float* __restrict__ lsp, const float* __restrict__ frp,
                         ush* __restrict__ Fhl) {
  int g = blockIdx.x * 256 + threadIdx.x;
  int row = g / 288;
  int kk = (g - row * 288) * 8;
  int s = row / NF, m = row - s * NF;
  float reg = fmaxf(frp[0] * frp[0], 1e-10f);
  float nm = numb[row], dn = denb[row];
  float alpha = nm / fmaxf(dn + reg * nm, 1e-8f);
  float sa = expf(lsp[0]) * alpha;
  size_t o = ((size_t)s * 576 + m) * (2 * K9) + (kk >> 5) * 64 + (kk & 31);
  ush8 gh = *(const ush8*)(FGhl + o);
  ush8 gl = *(const ush8*)(FGhl + o + 32);
  float4* Fp = (float4*)(F + (size_t)row * K9 + kk);
  float4 a = Fp[0], b = Fp[1];
  float f[8] = {a.x, a.y, a.z, a.w, b.x, b.y, b.z, b.w};
  ush8 h, lo;
#pragma unroll
  for (int i = 0; i < 8; ++i) {
    f[i] -= sa * (bf2f(gh[i]) + bf2f(gl[i]));
    ush hh = f2bf(f[i]);
    h[i] = hh;
    lo[i] = f2bf(f[i] - bf2f(hh));
  }
  Fp[0] = (float4){f[0], f[1], f[2], f[3]};
  Fp[1] = (float4){f[4], f[5], f[6], f[7]};
  *(ush8*)(Fhl + o) = h;
  *(ush8*)(Fhl + o + 32) = lo;
}

// ---------------- driver ----------------
extern "C" void kernel_launch(void* const* d_in, const int* in_sizes, int n_in,
                              void* d_out, int out_size, void* d_ws, size_t ws_size,
                              hipStream_t stream) {
  const float* filt = (const float*)d_in[0];
  const float* feat = (const float*)d_in[1];
  const float* wl   = (const float*)d_in[2];
  const float* wsp  = (const float*)d_in[3];
  const float* lsp  = (const float*)d_in[4];
  const float* frp  = (const float*)d_in[5];
  float* F = (float*)d_out;

  float* fb       = (float*)d_ws;
  float* labelF   = fb;
  float* spatialF = fb + 2048;
  float* numden   = fb + 4096;             // [2 iters][num|den][4240]
  ush* cur = (ush*)(fb + 4096 + 4 * 4240);

  const size_t szF  = (size_t)8 * 576 * (2 * K9);   // 21,233,664
  const size_t szXT = (size_t)8 * 640 * (2 * K9);   // 23,592,960
  const size_t szXb = (size_t)8 * K9 * (2 * NP);    // 20,054,016
  const size_t szRb = (size_t)8 * 640 * (2 * NP);   //  5,570,560
  const size_t szMb = (size_t)8 * NF * NP;          //  2,302,208

  // Order matters: Fhl and FGhl are A-operands whose 128-row tiles overrun by
  // up to 63 rows for the last sample — the following tensor absorbs the
  // (discarded) reads. Cp (exact-sized) goes last.
  ush* Fhl  = cur;           cur += szF;
  ush* FGhl = cur;           cur += szF;
  ush* XThl = cur;           cur += szXT;
  ush* Xbhl = cur;           cur += szXb;
  ush* Rbhl = cur;           cur += szRb;
  ush* Mb   = cur;           cur += szMb;
  float* Cp = (float*)(cur + (((size_t)cur) & 1 ? 1 : 0));  // align-ish (cur is ush*)
  Cp = (float*)((((size_t)cur) + 15) & ~(size_t)15);
  // Cp: 4*8*640*640 fp32 = 52.4 MB

  build_maps<<<8, 256, 0, stream>>>(wl, wsp, labelF, spatialF);
  hipMemsetAsync(numden, 0, 4 * 4240 * sizeof(float), stream);
  convert_f<<<4761, 256, 0, stream>>>(filt, F, Fhl);
  im2col_pack<<<dim3(10, 36, 8), 256, 0, stream>>>(feat, Xbhl, XThl);

  for (int it = 0; it < 2; ++it) {
    float* numb = numden + it * 2 * 4240;
    float* denb = numb + 4240;
    // scores partials (3-product split bf16), SK=4, 128x128 -> Cp
    gemm128<K9, 2, 2, 0, 4, 18, 25, 5><<<800, 256, 0, stream>>>(
        Fhl, XThl, Cp, nullptr, nullptr, nullptr, nullptr, 576);
    reduce_epi1<<<8 * NF, 256, 0, stream>>>(Cp, labelF, spatialF, Rbhl, Mb);
    // filter_grad = R*X^T + reg*F (3-product), direct K=544, 128x128 -> FGhl + num
    gemm128<NP, 2, 2, 2, 1, 17, 90, 5><<<720, 256, 0, stream>>>(
        Rbhl, Xbhl, nullptr, F, frp, FGhl, numb, 640);
    // scores_grad partials (2-product: A split, B hi), SK=4 -> Cp
    gemm128<K9, 2, 1, 0, 4, 18, 25, 5><<<800, 256, 0, stream>>>(
        FGhl, XThl, Cp, nullptr, nullptr, nullptr, nullptr, 576);
    reduce_epi3<<<8 * NF, 256, 0, stream>>>(Cp, spatialF, Mb, denb);
    update_f<<<4761, 256, 0, stream>>>(F, FGhl, numb, denb, lsp, frp, Fhl);
  }
}

// Round 9
// 541.227 us; speedup vs baseline: 2.6250x; 1.0169x over previous
//
#include <hip/hip_runtime.h>
#include <math.h>

#define NF   529
#define K9   2304
#define NP   544
#define DMAP 45

typedef unsigned short ush;
typedef unsigned int u32;
typedef __bf16 bf8_t __attribute__((ext_vector_type(8)));
typedef float f4_t __attribute__((ext_vector_type(4)));
typedef ush ush8 __attribute__((ext_vector_type(8)));

// Interleaved split layout: tensor[row][K/32][plane(hi,lo)][32] ush. Row stride 2*K.

__device__ __forceinline__ ush f2bf(float f) {
  union { float f; u32 u; } v; v.f = f;
  u32 r = v.u + 0x7fffu + ((v.u >> 16) & 1u);
  return (ush)(r >> 16);
}
__device__ __forceinline__ float bf2f(ush h) {
  union { u32 u; float f; } v; v.u = ((u32)h) << 16;
  return v.f;
}
__device__ __forceinline__ void async16(const void* g, void* l) {
  __builtin_amdgcn_global_load_lds((const __attribute__((address_space(1))) u32*)g,
                                   (__attribute__((address_space(3))) u32*)l, 16, 0, 0);
}

// ---------------- label / spatial map builder (45x45) ----------------
__global__ void build_maps(const float* __restrict__ wl, const float* __restrict__ wsp,
                           float* __restrict__ labelF, float* __restrict__ spatialF) {
  int idx = blockIdx.x * blockDim.x + threadIdx.x;
  if (idx >= DMAP * DMAP) return;
  int h = idx / DMAP, w = idx % DMAP;
  float dy = (float)(h - 22), dx = (float)(w - 22);
  float dist = sqrtf(dy * dy + dx * dx);
  float lab = 0.f, sp = 0.f;
#pragma unroll
  for (int b = 0; b < 9; ++b) {
    float bd = dist * 2.f - (float)b;
    float wt = fmaxf(0.f, 1.f - fabsf(bd));
    lab += wl[b] * wt;
    sp  += wsp[b] * wt;
  }
  float bd = dist * 2.f - 9.f;
  float wt = fminf(fmaxf(1.f + bd, 0.f), 1.f);
  lab += wl[9] * wt;
  sp  += wsp[9] * wt;
  labelF[idx] = lab;
  spatialF[idx] = sp;
}

// ---- convert filter -> fp32 copy (d_out) + interleaved hi/lo [s][576][2*2304] ----
__global__ void convert_f(const float* __restrict__ filt, float* __restrict__ F,
                          ush* __restrict__ Fhl) {
  int g = blockIdx.x * 256 + threadIdx.x;        // 4761 blocks
  int row = g / 288;
  int kk = (g - row * 288) * 8;
  int s = row / NF, m = row - s * NF;
  const float4* fp = (const float4*)(filt + (size_t)row * K9 + kk);
  float4 a = fp[0], b = fp[1];
  float4* Fp = (float4*)(F + (size_t)row * K9 + kk);
  Fp[0] = a; Fp[1] = b;
  float vv[8] = {a.x, a.y, a.z, a.w, b.x, b.y, b.z, b.w};
  ush8 h, lo;
#pragma unroll
  for (int i = 0; i < 8; ++i) {
    ush hh = f2bf(vv[i]);
    h[i] = hh;
    lo[i] = f2bf(vv[i] - bf2f(hh));
  }
  size_t o = ((size_t)s * 576 + m) * (2 * K9) + (kk >> 5) * 64 + (kk & 31);
  *(ush8*)(Fhl + o) = h;
  *(ush8*)(Fhl + o + 32) = lo;
}

// ---- im2col + pack: Xbhl[s][2304][2*544], XThl[s][640][2*2304] ----
__global__ void im2col_pack(const float* __restrict__ feat,
                            ush* __restrict__ Xbhl, ush* __restrict__ XThl) {
  __shared__ float T[64][65];
  int s = blockIdx.z, k0 = blockIdx.y * 64, yx0 = blockIdx.x * 64;
  int t = threadIdx.x;
  int r = t >> 2, c4 = (t & 3) * 16;
  int k = k0 + r;
  int ck = k / 9, j = k - ck * 9;
  int dy = j / 3 - 1, dx = j - (j / 3) * 3 - 1;
  const float* fb = feat + ((size_t)s * 256 + ck) * 529;
  float v[16];
#pragma unroll
  for (int i = 0; i < 16; ++i) {
    int yx = yx0 + c4 + i;
    float vv = 0.f;
    if (yx < NF) {
      int yy = yx / 23;
      int y = yy + dy, x = yx - yy * 23 + dx;
      if (y >= 0 && y < 23 && x >= 0 && x < 23) vv = fb[y * 23 + x];
    }
    v[i] = vv;
    T[r][c4 + i] = vv;
  }
  int c0 = yx0 + c4;
  if (c0 < NP) {
    size_t o = ((size_t)s * K9 + k) * (2 * NP) + (c0 >> 5) * 64 + (c0 & 31);
    ush8 h[2], lo[2];
#pragma unroll
    for (int gg = 0; gg < 2; ++gg)
#pragma unroll
      for (int i = 0; i < 8; ++i) {
        float vv = v[gg * 8 + i];
        ush hh = f2bf(vv);
        h[gg][i] = hh;
        lo[gg][i] = f2bf(vv - bf2f(hh));
      }
    *(ush8*)(Xbhl + o) = h[0];
    *(ush8*)(Xbhl + o + 8) = h[1];
    *(ush8*)(Xbhl + o + 32) = lo[0];
    *(ush8*)(Xbhl + o + 40) = lo[1];
  }
  __syncthreads();
  int kc = k0 + c4;
  size_t o2 = ((size_t)s * 640 + yx0 + r) * (2 * K9) + (kc >> 5) * 64 + (kc & 31);
  ush8 h2[2], l2[2];
#pragma unroll
  for (int gg = 0; gg < 2; ++gg)
#pragma unroll
    for (int i = 0; i < 8; ++i) {
      float vv = T[c4 + gg * 8 + i][r];
      ush hh = f2bf(vv);
      h2[gg][i] = hh;
      l2[gg][i] = f2bf(vv - bf2f(hh));
    }
  *(ush8*)(XThl + o2) = h2[0];
  *(ush8*)(XThl + o2 + 8) = h2[1];
  *(ush8*)(XThl + o2 + 32) = l2[0];
  *(ush8*)(XThl + o2 + 40) = l2[1];
}

// ------------- MFMA GEMM, 128x128 tile, single-buffer LDS, XOR-swizzled banks -------------
// LDS layout per 64-row group: element (row, kseg s) stored at slot t=(s+(row>>1))&3,
// byte row*64 + t*16. Staging lane l (row=w*16+(l>>2), slot l&3) fetches global seg
// ((l&3)-(l>>3))&3. Reads use slot (q+(c>>1))&3 -> 2-way banks (free, m136).
// MODE=0: fp32 partials Cp[sk*8+s][640][640].  MODE=2: filter_grad epilogue (+reg*F, num).
template <int KTOT, int ASPL, int BSPL, int MODE, int SKC, int CH, int BPG, int GX>
__launch_bounds__(256, 4)
__global__ void gemm128(const ush* __restrict__ Ahl, const ush* __restrict__ Bhl,
                        float* __restrict__ Cp,
                        const float* __restrict__ F, const float* __restrict__ frp,
                        ush* __restrict__ FGhl, float* __restrict__ numb,
                        const int arows) {
  __shared__ ush As[ASPL][128 * 32];
  __shared__ ush Bs[BSPL][128 * 32];

  const int tid = threadIdx.x;
  const int w = tid >> 6, l = tid & 63;
  const int wm = w & 1, wn = w >> 1;
  const int q = l >> 4, c = l & 15;

  const int xcd = blockIdx.x & 7;
  const int t = blockIdx.x >> 3;
  const int g = xcd + 8 * (t / BPG);
  const int j = t % BPG;
  const int s = g / SKC, sk = g % SKC;
  const int x = j % GX, y = j / GX;
  const int m0 = x * 128, n0 = y * 128;

  const ush* A0 = Ahl + (size_t)s * arows * (2 * KTOT);
  const ush* B0 = Bhl + (size_t)s * ((MODE == 2) ? K9 : 640) * (2 * KTOT);

  const int srow = w * 16 + (l >> 2);           // 0..63 within group
  const int scol = (l & 3) * 8;                 // LDS slot (fixed by DMA)
  const int ssw  = ((((l & 3) - (l >> 3)) & 3)) * 8;  // swizzled global seg

  f4_t acc[4][4];
#pragma unroll
  for (int i = 0; i < 4; ++i)
#pragma unroll
    for (int jj = 0; jj < 4; ++jj) acc[i][jj] = (f4_t){0.f, 0.f, 0.f, 0.f};

  for (int ch = 0; ch < CH; ++ch) {
    const int k2 = (sk * CH + ch) * 64;
#pragma unroll
    for (int i = 0; i < 2; ++i) {
      size_t ro = (size_t)(m0 + i * 64 + srow) * (2 * KTOT) + k2 + ssw;
      async16(A0 + ro, &As[0][(i * 64 + srow) * 32 + scol]);
      if (ASPL == 2) async16(A0 + ro + 32, &As[1][(i * 64 + srow) * 32 + scol]);
    }
#pragma unroll
    for (int i = 0; i < 2; ++i) {
      size_t ro = (size_t)(n0 + i * 64 + srow) * (2 * KTOT) + k2 + ssw;
      async16(B0 + ro, &Bs[0][(i * 64 + srow) * 32 + scol]);
      if (BSPL == 2) async16(B0 + ro + 32, &Bs[1][(i * 64 + srow) * 32 + scol]);
    }
    __syncthreads();

    const int slotA = (((q + (c >> 1)) & 3)) * 8;
    bf8_t av[ASPL][4], bv[BSPL][4];
#pragma unroll
    for (int pp = 0; pp < ASPL; ++pp)
#pragma unroll
      for (int ti = 0; ti < 4; ++ti)
        av[pp][ti] = *(const bf8_t*)&As[pp][(wm * 64 + ti * 16 + c) * 32 + slotA];
#pragma unroll
    for (int pp = 0; pp < BSPL; ++pp)
#pragma unroll
      for (int tj = 0; tj < 4; ++tj)
        bv[pp][tj] = *(const bf8_t*)&Bs[pp][(wn * 64 + tj * 16 + c) * 32 + slotA];

#pragma unroll
    for (int ti = 0; ti < 4; ++ti)
#pragma unroll
      for (int tj = 0; tj < 4; ++tj) {
        acc[ti][tj] = __builtin_amdgcn_mfma_f32_16x16x32_bf16(av[0][ti], bv[0][tj], acc[ti][tj], 0, 0, 0);
        if (ASPL == 2)
          acc[ti][tj] = __builtin_amdgcn_mfma_f32_16x16x32_bf16(av[1][ti], bv[0][tj], acc[ti][tj], 0, 0, 0);
        if (BSPL == 2)
          acc[ti][tj] = __builtin_amdgcn_mfma_f32_16x16x32_bf16(av[0][ti], bv[1][tj], acc[ti][tj], 0, 0, 0);
      }
    __syncthreads();
  }

  if (MODE == 0) {
    float* C = Cp + (size_t)(sk * 8 + s) * 640 * 640;
#pragma unroll
    for (int ti = 0; ti < 4; ++ti)
#pragma unroll
      for (int tj = 0; tj < 4; ++tj)
#pragma unroll
        for (int r = 0; r < 4; ++r) {
          int m = m0 + wm * 64 + ti * 16 + q * 4 + r;
          int n = n0 + wn * 64 + tj * 16 + c;
          C[(size_t)m * 640 + n] = acc[ti][tj][r];
        }
  } else {
    float reg = fmaxf(frp[0] * frp[0], 1e-10f);
#pragma unroll
    for (int ti = 0; ti < 4; ++ti) {
      float ps[4] = {0.f, 0.f, 0.f, 0.f};
      int mb = m0 + wm * 64 + ti * 16 + q * 4;
#pragma unroll
      for (int tj = 0; tj < 4; ++tj) {
        int n = n0 + wn * 64 + tj * 16 + c;
#pragma unroll
        for (int r = 0; r < 4; ++r) {
          int m = mb + r;
          if (m < NF) {
            float v = acc[ti][tj][r] + reg * F[((size_t)s * NF + m) * K9 + n];
            size_t o = ((size_t)s * 576 + m) * (2 * K9) + ((n >> 5) * 64) + (n & 31);
            ush h = f2bf(v);
            FGhl[o] = h;
            FGhl[o + 32] = f2bf(v - bf2f(h));
            ps[r] += v * v;
          }
        }
      }
#pragma unroll
      for (int r = 0; r < 4; ++r) {
        float pp = ps[r];
        pp += __shfl_xor(pp, 1); pp += __shfl_xor(pp, 2);
        pp += __shfl_xor(pp, 4); pp += __shfl_xor(pp, 8);
        if (c == 0 && (mb + r) < NF) atomicAdd(&numb[s * NF + mb + r], pp);
      }
    }
  }
}

// ---- reduce partials (SK=4) + scores epilogue -> Rbhl, Mb. one block per (s,m) row ----
__global__ void reduce_epi1(const float* __restrict__ Cp,
                            const float* __restrict__ labelF, const float* __restrict__ spatialF,
                            ush* __restrict__ Rbhl, ush* __restrict__ Mb) {
  int row = blockIdx.x;             // 8*529
  int s = row / NF, m = row - s * NF;
  int a = m / 23, b = m - a * 23;
  const size_t sp = (size_t)8 * 640 * 640;
  const float* C = Cp + ((size_t)s * 640 + m) * 640;
  for (int n = threadIdx.x; n < NF; n += 256) {
    float v = C[n] + C[sp + n] + C[2 * sp + n] + C[3 * sp + n];
    int yy = n / 23, xx = n - yy * 23;
    int idx = (22 + yy - a) * DMAP + (22 + xx - b);
    float sw = spatialF[idx], lm = labelF[idx];
    float sa, msk;
    if (m == n) { sa = v; msk = 1.f; }
    else {
      sa = 0.5f * fabsf(v) + 0.5f * v;
      msk = (v > 0.f) ? 1.f : ((v < 0.f) ? 0.f : 0.5f);
    }
    float rv = msk * sw * sw * (sa - lm);
    size_t o = ((size_t)s * 640 + m) * (2 * NP) + ((n >> 5) * 64) + (n & 31);
    ush h = f2bf(rv);
    Rbhl[o] = h;
    Rbhl[o + 32] = f2bf(rv - bf2f(h));
    Mb[((size_t)s * NF + m) * NP + n] = f2bf(msk);
  }
}

// ---- reduce partials (SK=4) + den row-sum (deterministic, no atomics) ----
__global__ void reduce_epi3(const float* __restrict__ Cp,
                            const float* __restrict__ spatialF, const ush* __restrict__ Mb,
                            float* __restrict__ denb) {
  int row = blockIdx.x;             // 8*529
  int s = row / NF, m = row - s * NF;
  int a = m / 23, b = m - a * 23;
  const size_t sp = (size_t)8 * 640 * 640;
  const float* C = Cp + ((size_t)s * 640 + m) * 640;
  float ss = 0.f;
  for (int n = threadIdx.x; n < NF; n += 256) {
    float v = C[n] + C[sp + n] + C[2 * sp + n] + C[3 * sp + n];
    int yy = n / 23, xx = n - yy * 23;
    int idx = (22 + yy - a) * DMAP + (22 + xx - b);
    float sw = spatialF[idx];
    float msk = bf2f(Mb[((size_t)s * NF + m) * NP + n]);
    float z = sw * msk * v;
    ss += z * z;
  }
  __shared__ float red[256];
  red[threadIdx.x] = ss; __syncthreads();
  for (int st = 128; st > 0; st >>= 1) {
    if (threadIdx.x < st) red[threadIdx.x] += red[threadIdx.x + st];
    __syncthreads();
  }
  if (threadIdx.x == 0) denb[row] = red[0];
}

// ---------------- filter update (+ refresh interleaved F planes) ----------------
__global__ void update_f(float* __restrict__ F, const ush* __restrict__ FGhl,
                         const float* __restrict__ numb, const float* __restrict__ denb,
                         const float* __restrict__ lsp, const float* __restrict__ frp,
                         ush* __restrict__ Fhl) {
  int g = blockIdx.x * 256 + threadIdx.x;
  int row = g / 288;
  int kk = (g - row * 288) * 8;
  int s = row / NF, m = row - s * NF;
  float reg = fmaxf(frp[0] * frp[0], 1e-10f);
  float nm = numb[row], dn = denb[row];
  float alpha = nm / fmaxf(dn + reg * nm, 1e-8f);
  float sa = expf(lsp[0]) * alpha;
  size_t o = ((size_t)s * 576 + m) * (2 * K9) + (kk >> 5) * 64 + (kk & 31);
  ush8 gh = *(const ush8*)(FGhl + o);
  ush8 gl = *(const ush8*)(FGhl + o + 32);
  float4* Fp = (float4*)(F + (size_t)row * K9 + kk);
  float4 a = Fp[0], b = Fp[1];
  float f[8] = {a.x, a.y, a.z, a.w, b.x, b.y, b.z, b.w};
  ush8 h, lo;
#pragma unroll
  for (int i = 0; i < 8; ++i) {
    f[i] -= sa * (bf2f(gh[i]) + bf2f(gl[i]));
    ush hh = f2bf(f[i]);
    h[i] = hh;
    lo[i] = f2bf(f[i] - bf2f(hh));
  }
  Fp[0] = (float4){f[0], f[1], f[2], f[3]};
  Fp[1] = (float4){f[4], f[5], f[6], f[7]};
  *(ush8*)(Fhl + o) = h;
  *(ush8*)(Fhl + o + 32) = lo;
}

// ---------------- driver ----------------
extern "C" void kernel_launch(void* const* d_in, const int* in_sizes, int n_in,
                              void* d_out, int out_size, void* d_ws, size_t ws_size,
                              hipStream_t stream) {
  const float* filt = (const float*)d_in[0];
  const float* feat = (const float*)d_in[1];
  const float* wl   = (const float*)d_in[2];
  const float* wsp  = (const float*)d_in[3];
  const float* lsp  = (const float*)d_in[4];
  const float* frp  = (const float*)d_in[5];
  float* F = (float*)d_out;

  float* fb       = (float*)d_ws;
  float* labelF   = fb;
  float* spatialF = fb + 2048;
  float* numden   = fb + 4096;             // [2 iters][num|den][4240]
  ush* cur = (ush*)(fb + 4096 + 4 * 4240);

  const size_t szF  = (size_t)8 * 576 * (2 * K9);   // 21,233,664
  const size_t szXT = (size_t)8 * 640 * (2 * K9);   // 23,592,960
  const size_t szXb = (size_t)8 * K9 * (2 * NP);    // 20,054,016
  const size_t szRb = (size_t)8 * 640 * (2 * NP);   //  5,570,560
  const size_t szMb = (size_t)8 * NF * NP;          //  2,302,208

  // Order matters: Fhl and FGhl are A-operands whose 128-row tiles overrun by
  // up to 63 rows for the last sample — the following tensor absorbs the
  // (discarded) reads. Cp (exact-sized) goes last.
  ush* Fhl  = cur;           cur += szF;
  ush* FGhl = cur;           cur += szF;
  ush* XThl = cur;           cur += szXT;
  ush* Xbhl = cur;           cur += szXb;
  ush* Rbhl = cur;           cur += szRb;
  ush* Mb   = cur;           cur += szMb;
  float* Cp = (float*)((((size_t)cur) + 15) & ~(size_t)15);
  // Cp: 4*8*640*640 fp32 = 52.4 MB

  build_maps<<<8, 256, 0, stream>>>(wl, wsp, labelF, spatialF);
  hipMemsetAsync(numden, 0, 4 * 4240 * sizeof(float), stream);
  convert_f<<<4761, 256, 0, stream>>>(filt, F, Fhl);
  im2col_pack<<<dim3(10, 36, 8), 256, 0, stream>>>(feat, Xbhl, XThl);

  for (int it = 0; it < 2; ++it) {
    float* numb = numden + it * 2 * 4240;
    float* denb = numb + 4240;
    // scores partials (3-product split bf16), SK=4, 128x128 -> Cp
    gemm128<K9, 2, 2, 0, 4, 18, 25, 5><<<800, 256, 0, stream>>>(
        Fhl, XThl, Cp, nullptr, nullptr, nullptr, nullptr, 576);
    reduce_epi1<<<8 * NF, 256, 0, stream>>>(Cp, labelF, spatialF, Rbhl, Mb);
    // filter_grad = R*X^T + reg*F (3-product), direct K=544, 128x128 -> FGhl + num
    gemm128<NP, 2, 2, 2, 1, 17, 90, 5><<<720, 256, 0, stream>>>(
        Rbhl, Xbhl, nullptr, F, frp, FGhl, numb, 640);
    // scores_grad partials (2-product: A split, B hi), SK=4 -> Cp
    gemm128<K9, 2, 1, 0, 4, 18, 25, 5><<<800, 256, 0, stream>>>(
        FGhl, XThl, Cp, nullptr, nullptr, nullptr, nullptr, 576);
    reduce_epi3<<<8 * NF, 256, 0, stream>>>(Cp, spatialF, Mb, denb);
    update_f<<<4761, 256, 0, stream>>>(F, FGhl, numb, denb, lsp, frp, Fhl);
  }
}

// Round 10
// 517.222 us; speedup vs baseline: 2.7468x; 1.0464x over previous
//
#include <hip/hip_runtime.h>
#include <math.h>

#define NF   529
#define K9   2304
#define NP   544
#define DMAP 45

typedef unsigned short ush;
typedef unsigned int u32;
typedef __bf16 bf8_t __attribute__((ext_vector_type(8)));
typedef float f4_t __attribute__((ext_vector_type(4)));
typedef ush ush8 __attribute__((ext_vector_type(8)));

// Interleaved split layout: tensor[row][K/32][plane(hi,lo)][32] ush. Row stride 2*K.

__device__ __forceinline__ ush f2bf(float f) {
  union { float f; u32 u; } v; v.f = f;
  u32 r = v.u + 0x7fffu + ((v.u >> 16) & 1u);
  return (ush)(r >> 16);
}
__device__ __forceinline__ float bf2f(ush h) {
  union { u32 u; float f; } v; v.u = ((u32)h) << 16;
  return v.f;
}
__device__ __forceinline__ void async16(const void* g, void* l) {
  __builtin_amdgcn_global_load_lds((const __attribute__((address_space(1))) u32*)g,
                                   (__attribute__((address_space(3))) u32*)l, 16, 0, 0);
}

// ---------------- label / spatial map builder (45x45) ----------------
__global__ void build_maps(const float* __restrict__ wl, const float* __restrict__ wsp,
                           float* __restrict__ labelF, float* __restrict__ spatialF) {
  int idx = blockIdx.x * blockDim.x + threadIdx.x;
  if (idx >= DMAP * DMAP) return;
  int h = idx / DMAP, w = idx % DMAP;
  float dy = (float)(h - 22), dx = (float)(w - 22);
  float dist = sqrtf(dy * dy + dx * dx);
  float lab = 0.f, sp = 0.f;
#pragma unroll
  for (int b = 0; b < 9; ++b) {
    float bd = dist * 2.f - (float)b;
    float wt = fmaxf(0.f, 1.f - fabsf(bd));
    lab += wl[b] * wt;
    sp  += wsp[b] * wt;
  }
  float bd = dist * 2.f - 9.f;
  float wt = fminf(fmaxf(1.f + bd, 0.f), 1.f);
  lab += wl[9] * wt;
  sp  += wsp[9] * wt;
  labelF[idx] = lab;
  spatialF[idx] = sp;
}

// ---- convert filter -> fp32 copy (d_out) + interleaved hi/lo [s][576][2*2304] ----
__global__ void convert_f(const float* __restrict__ filt, float* __restrict__ F,
                          ush* __restrict__ Fhl) {
  int g = blockIdx.x * 256 + threadIdx.x;        // 4761 blocks
  int row = g / 288;
  int kk = (g - row * 288) * 8;
  int s = row / NF, m = row - s * NF;
  const float4* fp = (const float4*)(filt + (size_t)row * K9 + kk);
  float4 a = fp[0], b = fp[1];
  float4* Fp = (float4*)(F + (size_t)row * K9 + kk);
  Fp[0] = a; Fp[1] = b;
  float vv[8] = {a.x, a.y, a.z, a.w, b.x, b.y, b.z, b.w};
  ush8 h, lo;
#pragma unroll
  for (int i = 0; i < 8; ++i) {
    ush hh = f2bf(vv[i]);
    h[i] = hh;
    lo[i] = f2bf(vv[i] - bf2f(hh));
  }
  size_t o = ((size_t)s * 576 + m) * (2 * K9) + (kk >> 5) * 64 + (kk & 31);
  *(ush8*)(Fhl + o) = h;
  *(ush8*)(Fhl + o + 32) = lo;
}

// ---- im2col + pack: Xbhl[s][2304][2*544], XThl[s][640][2*2304] ----
__global__ void im2col_pack(const float* __restrict__ feat,
                            ush* __restrict__ Xbhl, ush* __restrict__ XThl) {
  __shared__ float T[64][65];
  int s = blockIdx.z, k0 = blockIdx.y * 64, yx0 = blockIdx.x * 64;
  int t = threadIdx.x;
  int r = t >> 2, c4 = (t & 3) * 16;
  int k = k0 + r;
  int ck = k / 9, j = k - ck * 9;
  int dy = j / 3 - 1, dx = j - (j / 3) * 3 - 1;
  const float* fb = feat + ((size_t)s * 256 + ck) * 529;
  float v[16];
#pragma unroll
  for (int i = 0; i < 16; ++i) {
    int yx = yx0 + c4 + i;
    float vv = 0.f;
    if (yx < NF) {
      int yy = yx / 23;
      int y = yy + dy, x = yx - yy * 23 + dx;
      if (y >= 0 && y < 23 && x >= 0 && x < 23) vv = fb[y * 23 + x];
    }
    v[i] = vv;
    T[r][c4 + i] = vv;
  }
  int c0 = yx0 + c4;
  if (c0 < NP) {
    size_t o = ((size_t)s * K9 + k) * (2 * NP) + (c0 >> 5) * 64 + (c0 & 31);
    ush8 h[2], lo[2];
#pragma unroll
    for (int gg = 0; gg < 2; ++gg)
#pragma unroll
      for (int i = 0; i < 8; ++i) {
        float vv = v[gg * 8 + i];
        ush hh = f2bf(vv);
        h[gg][i] = hh;
        lo[gg][i] = f2bf(vv - bf2f(hh));
      }
    *(ush8*)(Xbhl + o) = h[0];
    *(ush8*)(Xbhl + o + 8) = h[1];
    *(ush8*)(Xbhl + o + 32) = lo[0];
    *(ush8*)(Xbhl + o + 40) = lo[1];
  }
  __syncthreads();
  int kc = k0 + c4;
  size_t o2 = ((size_t)s * 640 + yx0 + r) * (2 * K9) + (kc >> 5) * 64 + (kc & 31);
  ush8 h2[2], l2[2];
#pragma unroll
  for (int gg = 0; gg < 2; ++gg)
#pragma unroll
    for (int i = 0; i < 8; ++i) {
      float vv = T[c4 + gg * 8 + i][r];
      ush hh = f2bf(vv);
      h2[gg][i] = hh;
      l2[gg][i] = f2bf(vv - bf2f(hh));
    }
  *(ush8*)(XThl + o2) = h2[0];
  *(ush8*)(XThl + o2 + 8) = h2[1];
  *(ush8*)(XThl + o2 + 32) = l2[0];
  *(ush8*)(XThl + o2 + 40) = l2[1];
}

// ------------- MFMA GEMM, 128x128 tile, single-buffer LDS, XOR-swizzled banks -------------
// MODE=0: fp32 partials Cp[sk*8+s][640][640] via NONTEMPORAL stores (no L2 pollution).
// MODE=2: filter_grad epilogue (+reg*F -> FGhl split, num atomicAdd) — cached stores.
template <int KTOT, int ASPL, int BSPL, int MODE, int SKC, int CH, int BPG, int GX>
__launch_bounds__(256, 4)
__global__ void gemm128(const ush* __restrict__ Ahl, const ush* __restrict__ Bhl,
                        float* __restrict__ Cp,
                        const float* __restrict__ F, const float* __restrict__ frp,
                        ush* __restrict__ FGhl, float* __restrict__ numb,
                        const int arows) {
  __shared__ ush As[ASPL][128 * 32];
  __shared__ ush Bs[BSPL][128 * 32];

  const int tid = threadIdx.x;
  const int w = tid >> 6, l = tid & 63;
  const int wm = w & 1, wn = w >> 1;
  const int q = l >> 4, c = l & 15;

  const int xcd = blockIdx.x & 7;
  const int t = blockIdx.x >> 3;
  const int g = xcd + 8 * (t / BPG);
  const int j = t % BPG;
  const int s = g / SKC, sk = g % SKC;
  const int x = j % GX, y = j / GX;
  const int m0 = x * 128, n0 = y * 128;

  const ush* A0 = Ahl + (size_t)s * arows * (2 * KTOT);
  const ush* B0 = Bhl + (size_t)s * ((MODE == 2) ? K9 : 640) * (2 * KTOT);

  const int srow = w * 16 + (l >> 2);           // 0..63 within group
  const int scol = (l & 3) * 8;                 // LDS slot (fixed by DMA)
  const int ssw  = ((((l & 3) - (l >> 3)) & 3)) * 8;  // swizzled global seg

  f4_t acc[4][4];
#pragma unroll
  for (int i = 0; i < 4; ++i)
#pragma unroll
    for (int jj = 0; jj < 4; ++jj) acc[i][jj] = (f4_t){0.f, 0.f, 0.f, 0.f};

  for (int ch = 0; ch < CH; ++ch) {
    const int k2 = (sk * CH + ch) * 64;
#pragma unroll
    for (int i = 0; i < 2; ++i) {
      size_t ro = (size_t)(m0 + i * 64 + srow) * (2 * KTOT) + k2 + ssw;
      async16(A0 + ro, &As[0][(i * 64 + srow) * 32 + scol]);
      if (ASPL == 2) async16(A0 + ro + 32, &As[1][(i * 64 + srow) * 32 + scol]);
    }
#pragma unroll
    for (int i = 0; i < 2; ++i) {
      size_t ro = (size_t)(n0 + i * 64 + srow) * (2 * KTOT) + k2 + ssw;
      async16(B0 + ro, &Bs[0][(i * 64 + srow) * 32 + scol]);
      if (BSPL == 2) async16(B0 + ro + 32, &Bs[1][(i * 64 + srow) * 32 + scol]);
    }
    __syncthreads();

    const int slotA = (((q + (c >> 1)) & 3)) * 8;
    bf8_t av[ASPL][4], bv[BSPL][4];
#pragma unroll
    for (int pp = 0; pp < ASPL; ++pp)
#pragma unroll
      for (int ti = 0; ti < 4; ++ti)
        av[pp][ti] = *(const bf8_t*)&As[pp][(wm * 64 + ti * 16 + c) * 32 + slotA];
#pragma unroll
    for (int pp = 0; pp < BSPL; ++pp)
#pragma unroll
      for (int tj = 0; tj < 4; ++tj)
        bv[pp][tj] = *(const bf8_t*)&Bs[pp][(wn * 64 + tj * 16 + c) * 32 + slotA];

#pragma unroll
    for (int ti = 0; ti < 4; ++ti)
#pragma unroll
      for (int tj = 0; tj < 4; ++tj) {
        acc[ti][tj] = __builtin_amdgcn_mfma_f32_16x16x32_bf16(av[0][ti], bv[0][tj], acc[ti][tj], 0, 0, 0);
        if (ASPL == 2)
          acc[ti][tj] = __builtin_amdgcn_mfma_f32_16x16x32_bf16(av[1][ti], bv[0][tj], acc[ti][tj], 0, 0, 0);
        if (BSPL == 2)
          acc[ti][tj] = __builtin_amdgcn_mfma_f32_16x16x32_bf16(av[0][ti], bv[1][tj], acc[ti][tj], 0, 0, 0);
      }
    __syncthreads();
  }

  if (MODE == 0) {
    float* C = Cp + (size_t)(sk * 8 + s) * 640 * 640;
#pragma unroll
    for (int ti = 0; ti < 4; ++ti)
#pragma unroll
      for (int tj = 0; tj < 4; ++tj)
#pragma unroll
        for (int r = 0; r < 4; ++r) {
          int m = m0 + wm * 64 + ti * 16 + q * 4 + r;
          int n = n0 + wn * 64 + tj * 16 + c;
          __builtin_nontemporal_store(acc[ti][tj][r], &C[(size_t)m * 640 + n]);
        }
  } else {
    float reg = fmaxf(frp[0] * frp[0], 1e-10f);
#pragma unroll
    for (int ti = 0; ti < 4; ++ti) {
      float ps[4] = {0.f, 0.f, 0.f, 0.f};
      int mb = m0 + wm * 64 + ti * 16 + q * 4;
#pragma unroll
      for (int tj = 0; tj < 4; ++tj) {
        int n = n0 + wn * 64 + tj * 16 + c;
#pragma unroll
        for (int r = 0; r < 4; ++r) {
          int m = mb + r;
          if (m < NF) {
            float v = acc[ti][tj][r] + reg * F[((size_t)s * NF + m) * K9 + n];
            size_t o = ((size_t)s * 576 + m) * (2 * K9) + ((n >> 5) * 64) + (n & 31);
            ush h = f2bf(v);
            FGhl[o] = h;
            FGhl[o + 32] = f2bf(v - bf2f(h));
            ps[r] += v * v;
          }
        }
      }
#pragma unroll
      for (int r = 0; r < 4; ++r) {
        float pp = ps[r];
        pp += __shfl_xor(pp, 1); pp += __shfl_xor(pp, 2);
        pp += __shfl_xor(pp, 4); pp += __shfl_xor(pp, 8);
        if (c == 0 && (mb + r) < NF) atomicAdd(&numb[s * NF + mb + r], pp);
      }
    }
  }
}

// ---- reduce partials (SK=4) + scores epilogue -> Rbhl, Mb. one block per (s,m) row ----
__global__ void reduce_epi1(const float* __restrict__ Cp,
                            const float* __restrict__ labelF, const float* __restrict__ spatialF,
                            ush* __restrict__ Rbhl, ush* __restrict__ Mb) {
  int row = blockIdx.x;             // 8*529
  int s = row / NF, m = row - s * NF;
  int a = m / 23, b = m - a * 23;
  const size_t sp = (size_t)8 * 640 * 640;
  const float* C = Cp + ((size_t)s * 640 + m) * 640;
  for (int n = threadIdx.x; n < NF; n += 256) {
    float v = __builtin_nontemporal_load(&C[n]) +
              __builtin_nontemporal_load(&C[sp + n]) +
              __builtin_nontemporal_load(&C[2 * sp + n]) +
              __builtin_nontemporal_load(&C[3 * sp + n]);
    int yy = n / 23, xx = n - yy * 23;
    int idx = (22 + yy - a) * DMAP + (22 + xx - b);
    float sw = spatialF[idx], lm = labelF[idx];
    float sa, msk;
    if (m == n) { sa = v; msk = 1.f; }
    else {
      sa = 0.5f * fabsf(v) + 0.5f * v;
      msk = (v > 0.f) ? 1.f : ((v < 0.f) ? 0.f : 0.5f);
    }
    float rv = msk * sw * sw * (sa - lm);
    size_t o = ((size_t)s * 640 + m) * (2 * NP) + ((n >> 5) * 64) + (n & 31);
    ush h = f2bf(rv);
    Rbhl[o] = h;
    Rbhl[o + 32] = f2bf(rv - bf2f(h));
    Mb[((size_t)s * NF + m) * NP + n] = f2bf(msk);
  }
}

// ---- reduce partials (SK=4) + den row-sum (deterministic, no atomics) ----
__global__ void reduce_epi3(const float* __restrict__ Cp,
                            const float* __restrict__ spatialF, const ush* __restrict__ Mb,
                            float* __restrict__ denb) {
  int row = blockIdx.x;             // 8*529
  int s = row / NF, m = row - s * NF;
  int a = m / 23, b = m - a * 23;
  const size_t sp = (size_t)8 * 640 * 640;
  const float* C = Cp + ((size_t)s * 640 + m) * 640;
  float ss = 0.f;
  for (int n = threadIdx.x; n < NF; n += 256) {
    float v = __builtin_nontemporal_load(&C[n]) +
              __builtin_nontemporal_load(&C[sp + n]) +
              __builtin_nontemporal_load(&C[2 * sp + n]) +
              __builtin_nontemporal_load(&C[3 * sp + n]);
    int yy = n / 23, xx = n - yy * 23;
    int idx = (22 + yy - a) * DMAP + (22 + xx - b);
    float sw = spatialF[idx];
    float msk = bf2f(Mb[((size_t)s * NF + m) * NP + n]);
    float z = sw * msk * v;
    ss += z * z;
  }
  __shared__ float red[256];
  red[threadIdx.x] = ss; __syncthreads();
  for (int st = 128; st > 0; st >>= 1) {
    if (threadIdx.x < st) red[threadIdx.x] += red[threadIdx.x + st];
    __syncthreads();
  }
  if (threadIdx.x == 0) denb[row] = red[0];
}

// ---------------- filter update (+ refresh interleaved F planes) ----------------
__global__ void update_f(float* __restrict__ F, const ush* __restrict__ FGhl,
                         const float* __restrict__ numb, const float* __restrict__ denb,
                         const float* __restrict__ lsp, const float* __restrict__ frp,
                         ush* __restrict__ Fhl) {
  int g = blockIdx.x * 256 + threadIdx.x;
  int row = g / 288;
  int kk = (g - row * 288) * 8;
  int s = row / NF, m = row - s * NF;
  float reg = fmaxf(frp[0] * frp[0], 1e-10f);
  float nm = numb[row], dn = denb[row];
  float alpha = nm / fmaxf(dn + reg * nm, 1e-8f);
  float sa = expf(lsp[0]) * alpha;
  size_t o = ((size_t)s * 576 + m) * (2 * K9) + (kk >> 5) * 64 + (kk & 31);
  ush8 gh = *(const ush8*)(FGhl + o);
  ush8 gl = *(const ush8*)(FGhl + o + 32);
  float4* Fp = (float4*)(F + (size_t)row * K9 + kk);
  float4 a = Fp[0], b = Fp[1];
  float f[8] = {a.x, a.y, a.z, a.w, b.x, b.y, b.z, b.w};
  ush8 h, lo;
#pragma unroll
  for (int i = 0; i < 8; ++i) {
    f[i] -= sa * (bf2f(gh[i]) + bf2f(gl[i]));
    ush hh = f2bf(f[i]);
    h[i] = hh;
    lo[i] = f2bf(f[i] - bf2f(hh));
  }
  Fp[0] = (float4){f[0], f[1], f[2], f[3]};
  Fp[1] = (float4){f[4], f[5], f[6], f[7]};
  *(ush8*)(Fhl + o) = h;
  *(ush8*)(Fhl + o + 32) = lo;
}

// ---------------- driver ----------------
extern "C" void kernel_launch(void* const* d_in, const int* in_sizes, int n_in,
                              void* d_out, int out_size, void* d_ws, size_t ws_size,
                              hipStream_t stream) {
  const float* filt = (const float*)d_in[0];
  const float* feat = (const float*)d_in[1];
  const float* wl   = (const float*)d_in[2];
  const float* wsp  = (const float*)d_in[3];
  const float* lsp  = (const float*)d_in[4];
  const float* frp  = (const float*)d_in[5];
  float* F = (float*)d_out;

  float* fb       = (float*)d_ws;
  float* labelF   = fb;
  float* spatialF = fb + 2048;
  float* numden   = fb + 4096;             // [2 iters][num|den][4240]
  ush* cur = (ush*)(fb + 4096 + 4 * 4240);

  const size_t szF  = (size_t)8 * 576 * (2 * K9);   // 21,233,664
  const size_t szXT = (size_t)8 * 640 * (2 * K9);   // 23,592,960
  const size_t szXb = (size_t)8 * K9 * (2 * NP);    // 20,054,016
  const size_t szRb = (size_t)8 * 640 * (2 * NP);   //  5,570,560
  const size_t szMb = (size_t)8 * NF * NP;          //  2,302,208

  // Order matters: Fhl and FGhl are A-operands whose 128-row tiles overrun by
  // up to 63 rows for the last sample — the following tensor absorbs the
  // (discarded) reads. Cp (exact-sized) goes last.
  ush* Fhl  = cur;           cur += szF;
  ush* FGhl = cur;           cur += szF;
  ush* XThl = cur;           cur += szXT;
  ush* Xbhl = cur;           cur += szXb;
  ush* Rbhl = cur;           cur += szRb;
  ush* Mb   = cur;           cur += szMb;
  float* Cp = (float*)((((size_t)cur) + 15) & ~(size_t)15);
  // Cp: 4*8*640*640 fp32 = 52.4 MB

  build_maps<<<8, 256, 0, stream>>>(wl, wsp, labelF, spatialF);
  hipMemsetAsync(numden, 0, 4 * 4240 * sizeof(float), stream);
  convert_f<<<4761, 256, 0, stream>>>(filt, F, Fhl);
  im2col_pack<<<dim3(10, 36, 8), 256, 0, stream>>>(feat, Xbhl, XThl);

  for (int it = 0; it < 2; ++it) {
    float* numb = numden + it * 2 * 4240;
    float* denb = numb + 4240;
    // scores partials (3-product split bf16), SK=4, 128x128 -> Cp (NT stores)
    gemm128<K9, 2, 2, 0, 4, 18, 25, 5><<<800, 256, 0, stream>>>(
        Fhl, XThl, Cp, nullptr, nullptr, nullptr, nullptr, 576);
    reduce_epi1<<<8 * NF, 256, 0, stream>>>(Cp, labelF, spatialF, Rbhl, Mb);
    // filter_grad = R*X^T + reg*F (3-product), direct K=544, 128x128 -> FGhl + num
    gemm128<NP, 2, 2, 2, 1, 17, 90, 5><<<720, 256, 0, stream>>>(
        Rbhl, Xbhl, nullptr, F, frp, FGhl, numb, 640);
    // scores_grad partials (1-product bf16-hi: den tolerates incoherent rounding), SK=4 -> Cp
    gemm128<K9, 1, 1, 0, 4, 18, 25, 5><<<800, 256, 0, stream>>>(
        FGhl, XThl, Cp, nullptr, nullptr, nullptr, nullptr, 576);
    reduce_epi3<<<8 * NF, 256, 0, stream>>>(Cp, spatialF, Mb, denb);
    update_f<<<4761, 256, 0, stream>>>(F, FGhl, numb, denb, lsp, frp, Fhl);
  }
}